// Round 3
// baseline (364.251 us; speedup 1.0000x reference)
//
#include <hip/hip_runtime.h>

#define NO 8192
#define NTRAIN 100000
#define DIM 256
#define KNN 16

// ws layout (float offsets) — total ~1.07 MB
#define WS_VSRC 0
#define WS_VDST 256
#define WS_B12  512
#define WS_WCONV 768        // [ci][t][co] : (ci*5+t)*16+co, 1280 floats
#define WS_WSUM 2048        // [t][co] : t*16+co, 80 floats
#define WS_KB   2128        // 16
#define WS_C1W  2144        // 3
#define WS_C1B  2147        // 1
#define WS_W12  4096        // [1025][256] floats = 262400

// ---------------- K0: small precomputes ----------------
__global__ __launch_bounds__(256) void k0_prep(
    const float* __restrict__ Watt, const float* __restrict__ asrc, const float* __restrict__ adst,
    const float* __restrict__ b1, const float* __restrict__ w2, const float* __restrict__ b2,
    const float* __restrict__ c1w, const float* __restrict__ c1b,
    const float* __restrict__ ckw, const float* __restrict__ ckb,
    float* __restrict__ ws){
  int tid = threadIdx.x;
  int b = blockIdx.x;
  if (b < 2){
    __shared__ float a_sh[256];
    const float* av = (b==0) ? asrc : adst;
    a_sh[tid] = av[tid];
    __syncthreads();
    const float4* wp = (const float4*)(Watt + tid*DIM);
    float s = 0.f;
    for (int i=0;i<DIM/4;i++){
      float4 u = wp[i];
      int o = i*4;
      s += u.x*a_sh[o+0] + u.y*a_sh[o+1] + u.z*a_sh[o+2] + u.w*a_sh[o+3];
    }
    ws[(b==0?WS_VSRC:WS_VDST) + tid] = s;
  } else if (b == 2){
    float s = b2[tid];
    for (int h=0; h<512; ++h) s += b1[h] * w2[h*256+tid];
    ws[WS_B12+tid] = s;
  } else {
    for (int idx=tid; idx<1280; idx+=256){
      int co = idx/80, r = idx%80; int ci = r/5, t = r%5;
      ws[WS_WCONV + (ci*5+t)*16 + co] = ckw[idx];
    }
    __syncthreads();
    if (tid < 80){
      int t = tid/16, co = tid%16;
      float s = 0.f;
      for (int ci=0;ci<16;ci++) s += ws[WS_WCONV + (ci*5+t)*16 + co];
      ws[WS_WSUM + t*16 + co] = s;
    }
    if (tid < 16) ws[WS_KB + tid] = ckb[tid];
    if (tid < 3)  ws[WS_C1W + tid] = c1w[tid];
    if (tid == 3) ws[WS_C1B] = c1b[0];
  }
}

// ---------------- K1: fold W12 = w1 @ w2  ([1025][256]) ----------------
__global__ __launch_bounds__(256) void k1_fold(
    const float* __restrict__ w1, const float* __restrict__ w2, float* __restrict__ w12){
  __shared__ float aT[16][20];
  int tid = threadIdx.x;
  int r0 = blockIdx.x * 16;
  float acc[16];
  #pragma unroll
  for (int j=0;j<16;j++) acc[j] = 0.f;
  int kk = tid & 15, rr = tid >> 4;
  for (int kt=0; kt<32; ++kt){
    int row = r0 + rr;
    float av = (row < 1025) ? w1[row*512 + kt*16 + kk] : 0.f;
    __syncthreads();
    aT[kk][rr] = av;
    __syncthreads();
    #pragma unroll
    for (int k=0;k<16;++k){
      float bv = w2[(kt*16+k)*256 + tid];
      const float* a = aT[k];
      #pragma unroll
      for (int j=0;j<16;j++) acc[j] = fmaf(a[j], bv, acc[j]);
    }
  }
  #pragma unroll
  for (int j=0;j<16;j++){
    int row = r0 + j;
    if (row < 1025) w12[(size_t)row*256 + tid] = acc[j];
  }
}

// ---------------- K2: fully fused per-row kernel ----------------
__device__ float inter_full(int l2, const float* x_sh, const float (*cand)[256],
                            const float* __restrict__ wcv, const float* __restrict__ kb){
  float acc[16];
  #pragma unroll
  for (int j=0;j<16;j++) acc[j] = kb[j];
  for (int ci=0; ci<16; ++ci){
    const float* wci = wcv + ci*80;
    #pragma unroll
    for (int t=0;t<5;++t){
      int pos = l2 + t - 2;
      float v;
      if (pos < 0 || pos >= 512) v = 0.f;
      else if (pos < 256) v = x_sh[pos];
      else v = cand[ci][pos-256];
      const float* wb = wci + t*16;
      #pragma unroll
      for (int j=0;j<16;j++) acc[j] = fmaf(v, wb[j], acc[j]);
    }
  }
  float m = acc[0];
  #pragma unroll
  for (int j=1;j<16;j++) m = fmaxf(m, acc[j]);
  return m;
}

__global__ __launch_bounds__(256) void k2_fused(
    const float* __restrict__ X, const float* __restrict__ Xtr, const float* __restrict__ ytr,
    const float* __restrict__ ndist, const float* __restrict__ mtr, const float* __restrict__ mb,
    const int* __restrict__ nind,
    const float* __restrict__ ws,
    const float* __restrict__ w3, const float* __restrict__ b3,
    float* __restrict__ out0, float* __restrict__ outA, float* __restrict__ outB){
  __shared__ float x_sh[256];
  __shared__ float cand_sh[16][256];
  __shared__ float in_sh[1026];
  __shared__ float wgt_sh[16];
  __shared__ int   idx_sh[16];
  __shared__ float red_sh[4];
  __shared__ float hx_sh, pred_sh;
  __shared__ float hc_sh[16];

  int n = blockIdx.x;
  int tid = threadIdx.x;
  const float* vsrc = ws + WS_VSRC;
  const float* vdst = ws + WS_VDST;
  const float* wcv  = ws + WS_WCONV;
  const float* wsum = ws + WS_WSUM;
  const float* kb   = ws + WS_KB;

  float xv = X[n*256+tid];
  x_sh[tid] = xv;
  float xm = xv * mb[n*256+tid];
  float part = xm * vsrc[tid];
  #pragma unroll
  for (int off=32; off; off>>=1) part += __shfl_xor(part, off, 64);
  if ((tid&63)==0) red_sh[tid>>6] = part;
  __syncthreads();
  if (tid==0) hx_sh = red_sh[0]+red_sh[1]+red_sh[2]+red_sh[3];
  if (tid<16){
    int j = nind[n*16+tid];
    idx_sh[tid] = j;
    float d = ndist[n*16+tid];
    float inv = 1.f/(d + 1e-8f);
    float s = inv;
    #pragma unroll
    for (int off=8; off; off>>=1) s += __shfl_xor(s, off, 16);
    float w = inv/s;
    wgt_sh[tid] = w;
    float pp = ytr[j] * w;
    #pragma unroll
    for (int off=8; off; off>>=1) pp += __shfl_xor(pp, off, 16);
    if (tid==0) pred_sh = pp;
  }
  __syncthreads();
  // gather candidates: Candidate = X_train[idx] * mask_train[idx]
  #pragma unroll 4
  for (int kk=0; kk<16; ++kk){
    size_t basei = (size_t)idx_sh[kk]*256 + tid;
    cand_sh[kk][tid] = Xtr[basei] * mtr[basei];
  }
  __syncthreads();
  // h_c : 16 groups of 16 threads
  {
    int k = tid>>4, d0 = tid&15;
    float s = 0.f;
    #pragma unroll
    for (int i=0;i<16;i++){ int d = d0 + i*16; s += cand_sh[k][d]*vdst[d]; }
    #pragma unroll
    for (int off=8; off; off>>=1) s += __shfl_xor(s, off, 16);
    if (d0==0) hc_sh[k] = s;
  }
  __syncthreads();
  if (tid<16){
    float e = hx_sh + hc_sh[tid];
    e = (e>=0.f) ? e : 0.2f*e;
    outB[n*16+tid] = e;
    float m = e;
    #pragma unroll
    for (int off=8; off; off>>=1) m = fmaxf(m, __shfl_xor(m, off, 16));
    float ex = __expf(e - m);
    float ssum = ex;
    #pragma unroll
    for (int off=8; off; off>>=1) ssum += __shfl_xor(ssum, off, 16);
    outA[n*16+tid] = ex/ssum;
  }
  // scale candidates by weights -> Neighbors_o (h_c consumed raw cand already)
  #pragma unroll
  for (int k=0;k<16;k++) cand_sh[k][tid] *= wgt_sh[k];
  __syncthreads();

  // Neighbors conv (+max over co), position l = tid
  float acc[16];
  #pragma unroll
  for (int j=0;j<16;j++) acc[j] = kb[j];
  for (int ci=0; ci<16; ++ci){
    const float* wci = wcv + ci*80;
    #pragma unroll
    for (int t=0;t<5;++t){
      int pos = tid + t - 2;
      float v = cand_sh[ci][pos & 255];
      v = (pos >= 0 && pos < 256) ? v : 0.f;
      const float* wb = wci + t*16;
      #pragma unroll
      for (int j=0;j<16;j++) acc[j] = fmaf(v, wb[j], acc[j]);
    }
  }
  float nm = acc[0];
  #pragma unroll
  for (int j=1;j<16;j++) nm = fmaxf(nm, acc[j]);

  // Inter first half (positions 0..255): wsum trick for l<=253
  float im1;
  if (tid <= 253){
    float a2[16];
    #pragma unroll
    for (int j=0;j<16;j++) a2[j] = kb[j];
    #pragma unroll
    for (int t=0;t<5;++t){
      int pos = tid + t - 2;
      float v = x_sh[pos & 255];
      v = (pos >= 0) ? v : 0.f;
      const float* wb = wsum + t*16;
      #pragma unroll
      for (int j=0;j<16;j++) a2[j] = fmaf(v, wb[j], a2[j]);
    }
    im1 = a2[0];
    #pragma unroll
    for (int j=1;j<16;j++) im1 = fmaxf(im1, a2[j]);
  } else {
    im1 = inter_full(tid, x_sh, cand_sh, wcv, kb);
  }
  // Inter second half: Inter[256+l] == Neighbors[l] for l in [2,255]
  float im2 = (tid >= 2) ? nm : inter_full(256+tid, x_sh, cand_sh, wcv, kb);

  // X1: 3-tap conv of raw X
  float x1v = ws[WS_C1B];
  #pragma unroll
  for (int t=0;t<3;++t){
    int pos = tid + t - 1;
    float v = x_sh[pos & 255];
    v = (pos>=0 && pos<256) ? v : 0.f;
    x1v = fmaf(v, ws[WS_C1W+t], x1v);
  }

  // assemble inputs[1025] in LDS
  if (tid == 0) in_sh[0] = pred_sh;
  in_sh[1 + tid]       = x1v;
  in_sh[257 + tid]     = im1;
  in_sh[513 + tid]     = im2;
  in_sh[769 + tid]     = nm;
  __syncthreads();

  // fused MLP: z[tid] = b12[tid] + inputs . W12[:,tid]; relu; dot w3; relu; +pred
  float z = ws[WS_B12 + tid];
  const float* W12 = ws + WS_W12;
  for (int c=0; c<1024; c+=8){
    #pragma unroll
    for (int u=0;u<8;u++)
      z = fmaf(in_sh[c+u], W12[(size_t)(c+u)*256 + tid], z);
  }
  z = fmaf(in_sh[1024], W12[(size_t)1024*256 + tid], z);

  float p = fmaxf(z, 0.f) * w3[tid];
  #pragma unroll
  for (int off=32; off; off>>=1) p += __shfl_xor(p, off, 64);
  __syncthreads();
  if ((tid&63)==0) red_sh[tid>>6] = p;
  __syncthreads();
  if (tid == 0){
    float s = red_sh[0]+red_sh[1]+red_sh[2]+red_sh[3] + b3[0];
    float x3 = fmaxf(s, 0.f);
    out0[n] = pred_sh + x3;
  }
}

extern "C" void kernel_launch(void* const* d_in, const int* in_sizes, int n_in,
                              void* d_out, int out_size, void* d_ws, size_t ws_size,
                              hipStream_t stream){
  const float* X    = (const float*)d_in[0];
  const float* Xtr  = (const float*)d_in[1];
  const float* ytr  = (const float*)d_in[2];
  const float* nd   = (const float*)d_in[3];
  const float* mtr  = (const float*)d_in[4];
  const float* mb   = (const float*)d_in[5];
  const float* Watt = (const float*)d_in[6];
  const float* asrc = (const float*)d_in[7];
  const float* adst = (const float*)d_in[8];
  const float* w1   = (const float*)d_in[9];
  const float* b1   = (const float*)d_in[10];
  const float* w2   = (const float*)d_in[11];
  const float* b2   = (const float*)d_in[12];
  const float* w3   = (const float*)d_in[13];
  const float* b3   = (const float*)d_in[14];
  const float* c1w  = (const float*)d_in[15];
  const float* c1b  = (const float*)d_in[16];
  const float* ckw  = (const float*)d_in[17];
  const float* ckb  = (const float*)d_in[18];
  const int* nind = (const int*)d_in[19];
  float* ws = (float*)d_ws;
  float* out0 = (float*)d_out;
  float* outA = out0 + NO;
  float* outB = out0 + NO + NO*KNN;

  k0_prep<<<dim3(4), dim3(256), 0, stream>>>(Watt, asrc, adst, b1, w2, b2, c1w, c1b, ckw, ckb, ws);
  k1_fold<<<dim3(65), dim3(256), 0, stream>>>(w1, w2, ws + WS_W12);
  k2_fused<<<dim3(NO), dim3(256), 0, stream>>>(X, Xtr, ytr, nd, mtr, mb, nind,
                                               (const float*)ws, w3, b3,
                                               out0, outA, outB);
}

// Round 4
// 326.885 us; speedup vs baseline: 1.1143x; 1.1143x over previous
//
#include <hip/hip_runtime.h>

#define NO 8192
#define NTRAIN 100000
#define DIM 256
#define KNN 16
#define ROWS 8

// ws layout (float offsets) — total ~1.07 MB
#define WS_VSRC 0
#define WS_VDST 256
#define WS_B12  512
#define WS_WCONV 768        // [ci][t][co] : (ci*5+t)*16+co, 1280 floats
#define WS_WSUM 2048        // [t][co] : t*16+co, 80 floats
#define WS_KB   2128        // 16
#define WS_C1W  2144        // 3
#define WS_C1B  2147        // 1
#define WS_W12  4096        // [1025][256] floats = 262400

// ---------------- K0: small precomputes ----------------
__global__ __launch_bounds__(256) void k0_prep(
    const float* __restrict__ Watt, const float* __restrict__ asrc, const float* __restrict__ adst,
    const float* __restrict__ b1, const float* __restrict__ w2, const float* __restrict__ b2,
    const float* __restrict__ c1w, const float* __restrict__ c1b,
    const float* __restrict__ ckw, const float* __restrict__ ckb,
    float* __restrict__ ws){
  int tid = threadIdx.x;
  int b = blockIdx.x;
  if (b < 2){
    __shared__ float a_sh[256];
    const float* av = (b==0) ? asrc : adst;
    a_sh[tid] = av[tid];
    __syncthreads();
    const float4* wp = (const float4*)(Watt + tid*DIM);
    float s = 0.f;
    for (int i=0;i<DIM/4;i++){
      float4 u = wp[i];
      int o = i*4;
      s += u.x*a_sh[o+0] + u.y*a_sh[o+1] + u.z*a_sh[o+2] + u.w*a_sh[o+3];
    }
    ws[(b==0?WS_VSRC:WS_VDST) + tid] = s;
  } else if (b == 2){
    float s = b2[tid];
    for (int h=0; h<512; ++h) s += b1[h] * w2[h*256+tid];
    ws[WS_B12+tid] = s;
  } else {
    for (int idx=tid; idx<1280; idx+=256){
      int co = idx/80, r = idx%80; int ci = r/5, t = r%5;
      ws[WS_WCONV + (ci*5+t)*16 + co] = ckw[idx];
    }
    __syncthreads();
    if (tid < 80){
      int t = tid/16, co = tid%16;
      float s = 0.f;
      for (int ci=0;ci<16;ci++) s += ws[WS_WCONV + (ci*5+t)*16 + co];
      ws[WS_WSUM + t*16 + co] = s;
    }
    if (tid < 16) ws[WS_KB + tid] = ckb[tid];
    if (tid < 3)  ws[WS_C1W + tid] = c1w[tid];
    if (tid == 3) ws[WS_C1B] = c1b[0];
  }
}

// ---------------- K1: fold W12 = w1 @ w2  ([1025][256]) ----------------
__global__ __launch_bounds__(256) void k1_fold(
    const float* __restrict__ w1, const float* __restrict__ w2, float* __restrict__ w12){
  __shared__ float aT[16][20];
  int tid = threadIdx.x;
  int r0 = blockIdx.x * 16;
  float acc[16];
  #pragma unroll
  for (int j=0;j<16;j++) acc[j] = 0.f;
  int kk = tid & 15, rr = tid >> 4;
  for (int kt=0; kt<32; ++kt){
    int row = r0 + rr;
    float av = (row < 1025) ? w1[row*512 + kt*16 + kk] : 0.f;
    __syncthreads();
    aT[kk][rr] = av;
    __syncthreads();
    #pragma unroll
    for (int k=0;k<16;++k){
      float bv = w2[(kt*16+k)*256 + tid];
      const float* a = aT[k];
      #pragma unroll
      for (int j=0;j<16;j++) acc[j] = fmaf(a[j], bv, acc[j]);
    }
  }
  #pragma unroll
  for (int j=0;j<16;j++){
    int row = r0 + j;
    if (row < 1025) w12[(size_t)row*256 + tid] = acc[j];
  }
}

// ---------------- K2: fused, ROWS rows per block ----------------
__device__ float inter_full(int l2, const float* x_sh, const float (*cand)[256],
                            const float* __restrict__ wcv, const float* __restrict__ kb){
  float acc[16];
  #pragma unroll
  for (int j=0;j<16;j++) acc[j] = kb[j];
  for (int ci=0; ci<16; ++ci){
    const float* wci = wcv + ci*80;
    #pragma unroll
    for (int t=0;t<5;++t){
      int pos = l2 + t - 2;
      float v;
      if (pos < 0 || pos >= 512) v = 0.f;
      else if (pos < 256) v = x_sh[pos];
      else v = cand[ci][pos-256];
      const float* wb = wci + t*16;
      #pragma unroll
      for (int j=0;j<16;j++) acc[j] = fmaf(v, wb[j], acc[j]);
    }
  }
  float m = acc[0];
  #pragma unroll
  for (int j=1;j<16;j++) m = fmaxf(m, acc[j]);
  return m;
}

__global__ __launch_bounds__(256) void k2_fused(
    const float* __restrict__ X, const float* __restrict__ Xtr, const float* __restrict__ ytr,
    const float* __restrict__ ndist, const float* __restrict__ mtr, const float* __restrict__ mb,
    const int* __restrict__ nind,
    const float* __restrict__ ws,
    const float* __restrict__ w3, const float* __restrict__ b3,
    float* __restrict__ out0, float* __restrict__ outA, float* __restrict__ outB){
  __shared__ float x_sh[256];
  __shared__ float cand_sh[16][256];
  __shared__ __align__(16) float in_sh[ROWS][1028];
  __shared__ float wgt_sh[16];
  __shared__ int   idx_sh[16];
  __shared__ float red_sh[ROWS][4];
  __shared__ float hx_sh;
  __shared__ float pred_s[ROWS];
  __shared__ float hc_sh[16];

  int n0 = blockIdx.x * ROWS;
  int tid = threadIdx.x;
  const float* vsrc = ws + WS_VSRC;
  const float* vdst = ws + WS_VDST;
  const float* wcv  = ws + WS_WCONV;
  const float* wsum = ws + WS_WSUM;
  const float* kb   = ws + WS_KB;

  for (int r = 0; r < ROWS; ++r){
    int n = n0 + r;
    __syncthreads();   // protect x_sh/cand_sh reuse from previous row

    float xv = X[n*256+tid];
    x_sh[tid] = xv;
    float xm = xv * mb[n*256+tid];
    float part = xm * vsrc[tid];
    #pragma unroll
    for (int off=32; off; off>>=1) part += __shfl_xor(part, off, 64);
    if ((tid&63)==0) red_sh[0][tid>>6] = part;
    __syncthreads();
    if (tid==0) hx_sh = red_sh[0][0]+red_sh[0][1]+red_sh[0][2]+red_sh[0][3];
    if (tid<16){
      int j = nind[n*16+tid];
      idx_sh[tid] = j;
      float d = ndist[n*16+tid];
      float inv = 1.f/(d + 1e-8f);
      float s = inv;
      #pragma unroll
      for (int off=8; off; off>>=1) s += __shfl_xor(s, off, 16);
      float w = inv/s;
      wgt_sh[tid] = w;
      float pp = ytr[j] * w;
      #pragma unroll
      for (int off=8; off; off>>=1) pp += __shfl_xor(pp, off, 16);
      if (tid==0){ pred_s[r] = pp; in_sh[r][0] = pp; }
    }
    __syncthreads();
    // gather candidates (float4): wave w loads row k = g*4 + (tid>>6)
    {
      int kk4 = tid >> 6;
      int c4 = (tid & 63) * 4;
      #pragma unroll
      for (int g=0; g<4; ++g){
        int k = g*4 + kk4;
        size_t basei = (size_t)idx_sh[k]*256 + c4;
        float4 xv4 = *(const float4*)(Xtr + basei);
        float4 mv4 = *(const float4*)(mtr + basei);
        float4 cv;
        cv.x = xv4.x*mv4.x; cv.y = xv4.y*mv4.y; cv.z = xv4.z*mv4.z; cv.w = xv4.w*mv4.w;
        *(float4*)&cand_sh[k][c4] = cv;
      }
    }
    __syncthreads();
    // h_c : 16 groups of 16 threads
    {
      int k = tid>>4, d0 = tid&15;
      float s = 0.f;
      #pragma unroll
      for (int i=0;i<16;i++){ int d = d0 + i*16; s += cand_sh[k][d]*vdst[d]; }
      #pragma unroll
      for (int off=8; off; off>>=1) s += __shfl_xor(s, off, 16);
      if (d0==0) hc_sh[k] = s;
    }
    __syncthreads();
    if (tid<16){
      float e = hx_sh + hc_sh[tid];
      e = (e>=0.f) ? e : 0.2f*e;
      outB[n*16+tid] = e;
      float m = e;
      #pragma unroll
      for (int off=8; off; off>>=1) m = fmaxf(m, __shfl_xor(m, off, 16));
      float ex = __expf(e - m);
      float ssum = ex;
      #pragma unroll
      for (int off=8; off; off>>=1) ssum += __shfl_xor(ssum, off, 16);
      outA[n*16+tid] = ex/ssum;
    }
    // scale candidates by weights -> Neighbors_o
    #pragma unroll
    for (int k=0;k<16;k++) cand_sh[k][tid] *= wgt_sh[k];
    __syncthreads();

    // Neighbors conv (+max over co), position l = tid
    float acc[16];
    #pragma unroll
    for (int j=0;j<16;j++) acc[j] = kb[j];
    for (int ci=0; ci<16; ++ci){
      const float* wci = wcv + ci*80;
      #pragma unroll
      for (int t=0;t<5;++t){
        int pos = tid + t - 2;
        float v = cand_sh[ci][pos & 255];
        v = (pos >= 0 && pos < 256) ? v : 0.f;
        const float* wb = wci + t*16;
        #pragma unroll
        for (int j=0;j<16;j++) acc[j] = fmaf(v, wb[j], acc[j]);
      }
    }
    float nm = acc[0];
    #pragma unroll
    for (int j=1;j<16;j++) nm = fmaxf(nm, acc[j]);

    // Inter first half: wsum trick for l<=253
    float im1;
    if (tid <= 253){
      float a2[16];
      #pragma unroll
      for (int j=0;j<16;j++) a2[j] = kb[j];
      #pragma unroll
      for (int t=0;t<5;++t){
        int pos = tid + t - 2;
        float v = x_sh[pos & 255];
        v = (pos >= 0) ? v : 0.f;
        const float* wb = wsum + t*16;
        #pragma unroll
        for (int j=0;j<16;j++) a2[j] = fmaf(v, wb[j], a2[j]);
      }
      im1 = a2[0];
      #pragma unroll
      for (int j=1;j<16;j++) im1 = fmaxf(im1, a2[j]);
    } else {
      im1 = inter_full(tid, x_sh, cand_sh, wcv, kb);
    }
    // Inter second half: Inter[256+l] == Neighbors[l] for l in [2,255]
    float im2 = (tid >= 2) ? nm : inter_full(256+tid, x_sh, cand_sh, wcv, kb);

    // X1: 3-tap conv of raw X
    float x1v = ws[WS_C1B];
    #pragma unroll
    for (int t=0;t<3;++t){
      int pos = tid + t - 1;
      float v = x_sh[pos & 255];
      v = (pos>=0 && pos<256) ? v : 0.f;
      x1v = fmaf(v, ws[WS_C1W+t], x1v);
    }

    in_sh[r][1 + tid]   = x1v;
    in_sh[r][257 + tid] = im1;
    in_sh[r][513 + tid] = im2;
    in_sh[r][769 + tid] = nm;
  }
  __syncthreads();

  // fused MLP for ROWS rows: z[r] = b12[tid] + inputs[r] . W12[:,tid]
  const float* W12 = ws + WS_W12;
  float b12v = ws[WS_B12 + tid];
  float z[ROWS];
  #pragma unroll
  for (int r=0;r<ROWS;r++) z[r] = b12v;
  for (int c=0; c<1024; c+=4){
    float w0 = W12[(size_t)(c+0)*256 + tid];
    float w1v = W12[(size_t)(c+1)*256 + tid];
    float w2v = W12[(size_t)(c+2)*256 + tid];
    float w3v_ = W12[(size_t)(c+3)*256 + tid];
    #pragma unroll
    for (int r=0;r<ROWS;r++){
      float4 iv = *(const float4*)&in_sh[r][c];
      z[r] = fmaf(iv.x, w0, z[r]);
      z[r] = fmaf(iv.y, w1v, z[r]);
      z[r] = fmaf(iv.z, w2v, z[r]);
      z[r] = fmaf(iv.w, w3v_, z[r]);
    }
  }
  {
    float wl = W12[(size_t)1024*256 + tid];
    #pragma unroll
    for (int r=0;r<ROWS;r++) z[r] = fmaf(in_sh[r][1024], wl, z[r]);
  }

  float w3v = w3[tid];
  #pragma unroll
  for (int r=0;r<ROWS;r++){
    float p = fmaxf(z[r], 0.f) * w3v;
    #pragma unroll
    for (int off=32; off; off>>=1) p += __shfl_xor(p, off, 64);
    if ((tid&63)==0) red_sh[r][tid>>6] = p;
  }
  __syncthreads();
  if (tid < ROWS){
    float s = red_sh[tid][0]+red_sh[tid][1]+red_sh[tid][2]+red_sh[tid][3] + b3[0];
    float x3 = fmaxf(s, 0.f);
    out0[n0 + tid] = pred_s[tid] + x3;
  }
}

extern "C" void kernel_launch(void* const* d_in, const int* in_sizes, int n_in,
                              void* d_out, int out_size, void* d_ws, size_t ws_size,
                              hipStream_t stream){
  const float* X    = (const float*)d_in[0];
  const float* Xtr  = (const float*)d_in[1];
  const float* ytr  = (const float*)d_in[2];
  const float* nd   = (const float*)d_in[3];
  const float* mtr  = (const float*)d_in[4];
  const float* mb   = (const float*)d_in[5];
  const float* Watt = (const float*)d_in[6];
  const float* asrc = (const float*)d_in[7];
  const float* adst = (const float*)d_in[8];
  const float* w1   = (const float*)d_in[9];
  const float* b1   = (const float*)d_in[10];
  const float* w2   = (const float*)d_in[11];
  const float* b2   = (const float*)d_in[12];
  const float* w3   = (const float*)d_in[13];
  const float* b3   = (const float*)d_in[14];
  const float* c1w  = (const float*)d_in[15];
  const float* c1b  = (const float*)d_in[16];
  const float* ckw  = (const float*)d_in[17];
  const float* ckb  = (const float*)d_in[18];
  const int* nind = (const int*)d_in[19];
  float* ws = (float*)d_ws;
  float* out0 = (float*)d_out;
  float* outA = out0 + NO;
  float* outB = out0 + NO + NO*KNN;

  k0_prep<<<dim3(4), dim3(256), 0, stream>>>(Watt, asrc, adst, b1, w2, b2, c1w, c1b, ckw, ckb, ws);
  k1_fold<<<dim3(65), dim3(256), 0, stream>>>(w1, w2, ws + WS_W12);
  k2_fused<<<dim3(NO/ROWS), dim3(256), 0, stream>>>(X, Xtr, ytr, nd, mtr, mb, nind,
                                                    (const float*)ws, w3, b3,
                                                    out0, outA, outB);
}

// Round 5
// 241.892 us; speedup vs baseline: 1.5058x; 1.3514x over previous
//
#include <hip/hip_runtime.h>

#define NO 8192
#define NTRAIN 100000
#define DIM 256
#define KNN 16
#define ROWS 8

// ws layout (float offsets)
#define WS_VSRC 0
#define WS_VDST 256
#define WS_B12  512
#define WS_WCONV 768        // [ci][t][co] : (ci*5+t)*16+co, 1280 floats
#define WS_WSUM 2048        // [t][co] : t*16+co, 80 floats
#define WS_KB   2128        // 16
#define WS_C1W  2144        // 3
#define WS_C1B  2147        // 1
#define WS_W12  4096        // [1040][256] floats (rows >=1025 zeroed) = 266240
#define WS_INA  270336      // [8192][1040] floats = 8519680
#define WS_NEED_BYTES ((size_t)(WS_INA + (size_t)NO*1040) * 4)

// ---------------- K0: small precomputes ----------------
__global__ __launch_bounds__(256) void k0_prep(
    const float* __restrict__ Watt, const float* __restrict__ asrc, const float* __restrict__ adst,
    const float* __restrict__ b1, const float* __restrict__ w2, const float* __restrict__ b2,
    const float* __restrict__ c1w, const float* __restrict__ c1b,
    const float* __restrict__ ckw, const float* __restrict__ ckb,
    float* __restrict__ ws){
  int tid = threadIdx.x;
  int b = blockIdx.x;
  if (b < 2){
    __shared__ float a_sh[256];
    const float* av = (b==0) ? asrc : adst;
    a_sh[tid] = av[tid];
    __syncthreads();
    const float4* wp = (const float4*)(Watt + tid*DIM);
    float s = 0.f;
    for (int i=0;i<DIM/4;i++){
      float4 u = wp[i];
      int o = i*4;
      s += u.x*a_sh[o+0] + u.y*a_sh[o+1] + u.z*a_sh[o+2] + u.w*a_sh[o+3];
    }
    ws[(b==0?WS_VSRC:WS_VDST) + tid] = s;
  } else if (b == 2){
    float s = b2[tid];
    for (int h=0; h<512; ++h) s += b1[h] * w2[h*256+tid];
    ws[WS_B12+tid] = s;
  } else {
    for (int idx=tid; idx<1280; idx+=256){
      int co = idx/80, r = idx%80; int ci = r/5, t = r%5;
      ws[WS_WCONV + (ci*5+t)*16 + co] = ckw[idx];
    }
    __syncthreads();
    if (tid < 80){
      int t = tid/16, co = tid%16;
      float s = 0.f;
      for (int ci=0;ci<16;ci++) s += ws[WS_WCONV + (ci*5+t)*16 + co];
      ws[WS_WSUM + t*16 + co] = s;
    }
    if (tid < 16) ws[WS_KB + tid] = ckb[tid];
    if (tid < 3)  ws[WS_C1W + tid] = c1w[tid];
    if (tid == 3) ws[WS_C1B] = c1b[0];
  }
}

// ---------------- K1: fold W12 = w1 @ w2  ([1040][256], rows>=1025 zero) ----------------
__global__ __launch_bounds__(256) void k1_fold(
    const float* __restrict__ w1, const float* __restrict__ w2, float* __restrict__ w12){
  __shared__ float aT[16][20];
  int tid = threadIdx.x;
  int r0 = blockIdx.x * 16;
  float acc[16];
  #pragma unroll
  for (int j=0;j<16;j++) acc[j] = 0.f;
  int kk = tid & 15, rr = tid >> 4;
  for (int kt=0; kt<32; ++kt){
    int row = r0 + rr;
    float av = (row < 1025) ? w1[row*512 + kt*16 + kk] : 0.f;
    __syncthreads();
    aT[kk][rr] = av;
    __syncthreads();
    #pragma unroll
    for (int k=0;k<16;++k){
      float bv = w2[(kt*16+k)*256 + tid];
      const float* a = aT[k];
      #pragma unroll
      for (int j=0;j<16;j++) acc[j] = fmaf(a[j], bv, acc[j]);
    }
  }
  #pragma unroll
  for (int j=0;j<16;j++){
    int row = r0 + j;
    w12[(size_t)row*256 + tid] = (row < 1025) ? acc[j] : 0.f;
  }
}

// ---------------- K2a: stage-1, one row per block ----------------
__global__ __launch_bounds__(256) void k2a_stage(
    const float* __restrict__ X, const float* __restrict__ Xtr, const float* __restrict__ ytr,
    const float* __restrict__ ndist, const float* __restrict__ mtr, const float* __restrict__ mb,
    const int* __restrict__ nind,
    const float* __restrict__ ws, float* __restrict__ inA,
    float* __restrict__ outA, float* __restrict__ outB){
  __shared__ float x_sh[256];
  __shared__ float cand_sh[16][256];
  __shared__ float corr_sh[10][16];
  __shared__ float wgt_sh[16];
  __shared__ int   idx_sh[16];
  __shared__ float red_sh[4];
  __shared__ float hx_sh, pred_sh;
  __shared__ float hc_sh[16];

  int n = blockIdx.x;
  int tid = threadIdx.x;
  const float* vsrc = ws + WS_VSRC;
  const float* vdst = ws + WS_VDST;
  const float* wcv  = ws + WS_WCONV;
  const float* wsum = ws + WS_WSUM;
  const float* kb   = ws + WS_KB;

  float xv = X[n*256+tid];
  x_sh[tid] = xv;
  float xm = xv * mb[n*256+tid];
  float part = xm * vsrc[tid];
  #pragma unroll
  for (int off=32; off; off>>=1) part += __shfl_xor(part, off, 64);
  if ((tid&63)==0) red_sh[tid>>6] = part;
  __syncthreads();
  if (tid==0) hx_sh = red_sh[0]+red_sh[1]+red_sh[2]+red_sh[3];
  if (tid<16){
    int j = nind[n*16+tid];
    idx_sh[tid] = j;
    float d = ndist[n*16+tid];
    float inv = 1.f/(d + 1e-8f);
    float s = inv;
    #pragma unroll
    for (int off=8; off; off>>=1) s += __shfl_xor(s, off, 16);
    float w = inv/s;
    wgt_sh[tid] = w;
    float pp = ytr[j] * w;
    #pragma unroll
    for (int off=8; off; off>>=1) pp += __shfl_xor(pp, off, 16);
    if (tid==0) pred_sh = pp;
  }
  __syncthreads();
  // gather candidates (float4)
  {
    int kk4 = tid >> 6;
    int c4 = (tid & 63) * 4;
    #pragma unroll
    for (int g=0; g<4; ++g){
      int k = g*4 + kk4;
      size_t basei = (size_t)idx_sh[k]*256 + c4;
      float4 xv4 = *(const float4*)(Xtr + basei);
      float4 mv4 = *(const float4*)(mtr + basei);
      float4 cv;
      cv.x = xv4.x*mv4.x; cv.y = xv4.y*mv4.y; cv.z = xv4.z*mv4.z; cv.w = xv4.w*mv4.w;
      *(float4*)&cand_sh[k][c4] = cv;
    }
  }
  __syncthreads();
  // h_c : 16 groups of 16 threads
  {
    int k = tid>>4, d0 = tid&15;
    float s = 0.f;
    #pragma unroll
    for (int i=0;i<16;i++){ int d = d0 + i*16; s += cand_sh[k][d]*vdst[d]; }
    #pragma unroll
    for (int off=8; off; off>>=1) s += __shfl_xor(s, off, 16);
    if (d0==0) hc_sh[k] = s;
  }
  __syncthreads();
  if (tid<16){
    float e = hx_sh + hc_sh[tid];
    e = (e>=0.f) ? e : 0.2f*e;
    outB[n*16+tid] = e;
    float m = e;
    #pragma unroll
    for (int off=8; off; off>>=1) m = fmaxf(m, __shfl_xor(m, off, 16));
    float ex = __expf(e - m);
    float ssum = ex;
    #pragma unroll
    for (int off=8; off; off>>=1) ssum += __shfl_xor(ssum, off, 16);
    outA[n*16+tid] = ex/ssum;
  }
  // scale candidates by weights -> Neighbors_o
  #pragma unroll
  for (int k=0;k<16;k++) cand_sh[k][tid] *= wgt_sh[k];
  __syncthreads();

  // cooperative correction terms S[(t,p)][co] = sum_ci w[ci][t][co]*cand[ci][p]
  // pairs: im1 l=254:(4,0); l=255:(3,0),(4,1); im2 l2=256:(2,0),(3,1),(4,2); l2=257:(1,0),(2,1),(3,2),(4,3)
  if (tid < 160){
    const int tt[10] = {4,3,4,2,3,4,1,2,3,4};
    const int pp[10] = {0,0,1,0,1,2,0,1,2,3};
    int pair = tid >> 4, co = tid & 15;
    int t = tt[pair], p = pp[pair];
    float s = 0.f;
    #pragma unroll
    for (int ci=0; ci<16; ++ci) s += wcv[(ci*5+t)*16+co] * cand_sh[ci][p];
    corr_sh[pair][co] = s;
  }

  // Neighbors conv (+max over co), position l = tid
  float acc[16];
  #pragma unroll
  for (int j=0;j<16;j++) acc[j] = kb[j];
  for (int ci=0; ci<16; ++ci){
    const float* wci = wcv + ci*80;
    #pragma unroll
    for (int t=0;t<5;++t){
      int pos = tid + t - 2;
      float v = cand_sh[ci][pos & 255];
      v = (pos >= 0 && pos < 256) ? v : 0.f;
      const float* wb = wci + t*16;
      #pragma unroll
      for (int j=0;j<16;j++) acc[j] = fmaf(v, wb[j], acc[j]);
    }
  }
  float nm = acc[0];
  #pragma unroll
  for (int j=1;j<16;j++) nm = fmaxf(nm, acc[j]);

  // Inter first half via wsum (x zero-padded both sides), corr added below for l>=254
  float a2[16];
  #pragma unroll
  for (int j=0;j<16;j++) a2[j] = kb[j];
  #pragma unroll
  for (int t=0;t<5;++t){
    int pos = tid + t - 2;
    float v = x_sh[pos & 255];
    v = (pos >= 0 && pos < 256) ? v : 0.f;
    const float* wb = wsum + t*16;
    #pragma unroll
    for (int j=0;j<16;j++) a2[j] = fmaf(v, wb[j], a2[j]);
  }
  __syncthreads();   // corr_sh visible
  if (tid == 254){
    #pragma unroll
    for (int j=0;j<16;j++) a2[j] += corr_sh[0][j];
  }
  if (tid == 255){
    #pragma unroll
    for (int j=0;j<16;j++) a2[j] += corr_sh[1][j] + corr_sh[2][j];
  }
  float im1 = a2[0];
  #pragma unroll
  for (int j=1;j<16;j++) im1 = fmaxf(im1, a2[j]);

  // Inter second half: == Neighbors for l>=2; l=0,1 from wsum-x tail + corr
  float im2 = nm;
  if (tid < 2){
    float a3[16];
    if (tid == 0){
      #pragma unroll
      for (int j=0;j<16;j++)
        a3[j] = kb[j] + wsum[0*16+j]*x_sh[254] + wsum[1*16+j]*x_sh[255]
              + corr_sh[3][j] + corr_sh[4][j] + corr_sh[5][j];
    } else {
      #pragma unroll
      for (int j=0;j<16;j++)
        a3[j] = kb[j] + wsum[0*16+j]*x_sh[255]
              + corr_sh[6][j] + corr_sh[7][j] + corr_sh[8][j] + corr_sh[9][j];
    }
    im2 = a3[0];
    #pragma unroll
    for (int j=1;j<16;j++) im2 = fmaxf(im2, a3[j]);
  }

  // X1: 3-tap conv of raw X
  float x1v = ws[WS_C1B];
  #pragma unroll
  for (int t=0;t<3;++t){
    int pos = tid + t - 1;
    float v = x_sh[pos & 255];
    v = (pos>=0 && pos<256) ? v : 0.f;
    x1v = fmaf(v, ws[WS_C1W+t], x1v);
  }

  size_t base = (size_t)n*1040;
  inA[base + 1 + tid]   = x1v;
  inA[base + 257 + tid] = im1;
  inA[base + 513 + tid] = im2;
  inA[base + 769 + tid] = nm;
  if (tid == 0) inA[base] = pred_sh;
  if (tid < 15) inA[base + 1025 + tid] = 0.f;
}

// ---------------- K2b: GEMM inputs[8192x1040] @ W12[1040x256] + epilogue ----------------
__global__ __launch_bounds__(256) void k2b_mlp(
    const float* __restrict__ ws, const float* __restrict__ w3, const float* __restrict__ b3,
    float* __restrict__ out0){
  __shared__ float aT[16][20];
  __shared__ float red[16][4];
  int tid = threadIdx.x;
  int r0 = blockIdx.x * 16;
  const float* W12 = ws + WS_W12;
  const float* inA = ws + WS_INA;
  float b12v = ws[WS_B12 + tid];
  float acc[16];
  #pragma unroll
  for (int j=0;j<16;j++) acc[j] = b12v;
  int kk = tid & 15, rr = tid >> 4;
  for (int kt=0; kt<65; ++kt){
    float av = inA[(size_t)(r0+rr)*1040 + kt*16 + kk];
    __syncthreads();
    aT[kk][rr] = av;
    __syncthreads();
    #pragma unroll
    for (int k=0;k<16;++k){
      float bv = W12[(size_t)(kt*16+k)*256 + tid];
      const float* a = aT[k];
      #pragma unroll
      for (int j=0;j<16;j++) acc[j] = fmaf(a[j], bv, acc[j]);
    }
  }
  float w3v = w3[tid];
  #pragma unroll
  for (int j=0;j<16;j++){
    float p = fmaxf(acc[j], 0.f) * w3v;
    #pragma unroll
    for (int off=32; off; off>>=1) p += __shfl_xor(p, off, 64);
    if ((tid&63)==0) red[j][tid>>6] = p;
  }
  __syncthreads();
  if (tid < 16){
    float s = red[tid][0]+red[tid][1]+red[tid][2]+red[tid][3] + b3[0];
    float x3 = fmaxf(s, 0.f);
    out0[r0+tid] = inA[(size_t)(r0+tid)*1040] + x3;
  }
}

// ---------------- Fallback: fused (round-4) path ----------------
__global__ __launch_bounds__(256) void k2_fused(
    const float* __restrict__ X, const float* __restrict__ Xtr, const float* __restrict__ ytr,
    const float* __restrict__ ndist, const float* __restrict__ mtr, const float* __restrict__ mb,
    const int* __restrict__ nind,
    const float* __restrict__ ws,
    const float* __restrict__ w3, const float* __restrict__ b3,
    float* __restrict__ out0, float* __restrict__ outA, float* __restrict__ outB){
  __shared__ float x_sh[256];
  __shared__ float cand_sh[16][256];
  __shared__ __align__(16) float in_sh[ROWS][1028];
  __shared__ float corr_sh[10][16];
  __shared__ float wgt_sh[16];
  __shared__ int   idx_sh[16];
  __shared__ float red_sh[ROWS][4];
  __shared__ float hx_sh;
  __shared__ float pred_s[ROWS];
  __shared__ float hc_sh[16];

  int n0 = blockIdx.x * ROWS;
  int tid = threadIdx.x;
  const float* vsrc = ws + WS_VSRC;
  const float* vdst = ws + WS_VDST;
  const float* wcv  = ws + WS_WCONV;
  const float* wsum = ws + WS_WSUM;
  const float* kb   = ws + WS_KB;

  for (int r = 0; r < ROWS; ++r){
    int n = n0 + r;
    __syncthreads();

    float xv = X[n*256+tid];
    x_sh[tid] = xv;
    float xm = xv * mb[n*256+tid];
    float part = xm * vsrc[tid];
    #pragma unroll
    for (int off=32; off; off>>=1) part += __shfl_xor(part, off, 64);
    if ((tid&63)==0) red_sh[0][tid>>6] = part;
    __syncthreads();
    if (tid==0) hx_sh = red_sh[0][0]+red_sh[0][1]+red_sh[0][2]+red_sh[0][3];
    if (tid<16){
      int j = nind[n*16+tid];
      idx_sh[tid] = j;
      float d = ndist[n*16+tid];
      float inv = 1.f/(d + 1e-8f);
      float s = inv;
      #pragma unroll
      for (int off=8; off; off>>=1) s += __shfl_xor(s, off, 16);
      float w = inv/s;
      wgt_sh[tid] = w;
      float pp = ytr[j] * w;
      #pragma unroll
      for (int off=8; off; off>>=1) pp += __shfl_xor(pp, off, 16);
      if (tid==0){ pred_s[r] = pp; in_sh[r][0] = pp; }
    }
    __syncthreads();
    {
      int kk4 = tid >> 6;
      int c4 = (tid & 63) * 4;
      #pragma unroll
      for (int g=0; g<4; ++g){
        int k = g*4 + kk4;
        size_t basei = (size_t)idx_sh[k]*256 + c4;
        float4 xv4 = *(const float4*)(Xtr + basei);
        float4 mv4 = *(const float4*)(mtr + basei);
        float4 cv;
        cv.x = xv4.x*mv4.x; cv.y = xv4.y*mv4.y; cv.z = xv4.z*mv4.z; cv.w = xv4.w*mv4.w;
        *(float4*)&cand_sh[k][c4] = cv;
      }
    }
    __syncthreads();
    {
      int k = tid>>4, d0 = tid&15;
      float s = 0.f;
      #pragma unroll
      for (int i=0;i<16;i++){ int d = d0 + i*16; s += cand_sh[k][d]*vdst[d]; }
      #pragma unroll
      for (int off=8; off; off>>=1) s += __shfl_xor(s, off, 16);
      if (d0==0) hc_sh[k] = s;
    }
    __syncthreads();
    if (tid<16){
      float e = hx_sh + hc_sh[tid];
      e = (e>=0.f) ? e : 0.2f*e;
      outB[n*16+tid] = e;
      float m = e;
      #pragma unroll
      for (int off=8; off; off>>=1) m = fmaxf(m, __shfl_xor(m, off, 16));
      float ex = __expf(e - m);
      float ssum = ex;
      #pragma unroll
      for (int off=8; off; off>>=1) ssum += __shfl_xor(ssum, off, 16);
      outA[n*16+tid] = ex/ssum;
    }
    #pragma unroll
    for (int k=0;k<16;k++) cand_sh[k][tid] *= wgt_sh[k];
    __syncthreads();

    if (tid < 160){
      const int tt[10] = {4,3,4,2,3,4,1,2,3,4};
      const int pp[10] = {0,0,1,0,1,2,0,1,2,3};
      int pair = tid >> 4, co = tid & 15;
      int t = tt[pair], p = pp[pair];
      float s = 0.f;
      #pragma unroll
      for (int ci=0; ci<16; ++ci) s += wcv[(ci*5+t)*16+co] * cand_sh[ci][p];
      corr_sh[pair][co] = s;
    }

    float acc[16];
    #pragma unroll
    for (int j=0;j<16;j++) acc[j] = kb[j];
    for (int ci=0; ci<16; ++ci){
      const float* wci = wcv + ci*80;
      #pragma unroll
      for (int t=0;t<5;++t){
        int pos = tid + t - 2;
        float v = cand_sh[ci][pos & 255];
        v = (pos >= 0 && pos < 256) ? v : 0.f;
        const float* wb = wci + t*16;
        #pragma unroll
        for (int j=0;j<16;j++) acc[j] = fmaf(v, wb[j], acc[j]);
      }
    }
    float nm = acc[0];
    #pragma unroll
    for (int j=1;j<16;j++) nm = fmaxf(nm, acc[j]);

    float a2[16];
    #pragma unroll
    for (int j=0;j<16;j++) a2[j] = kb[j];
    #pragma unroll
    for (int t=0;t<5;++t){
      int pos = tid + t - 2;
      float v = x_sh[pos & 255];
      v = (pos >= 0 && pos < 256) ? v : 0.f;
      const float* wb = wsum + t*16;
      #pragma unroll
      for (int j=0;j<16;j++) a2[j] = fmaf(v, wb[j], a2[j]);
    }
    __syncthreads();
    if (tid == 254){
      #pragma unroll
      for (int j=0;j<16;j++) a2[j] += corr_sh[0][j];
    }
    if (tid == 255){
      #pragma unroll
      for (int j=0;j<16;j++) a2[j] += corr_sh[1][j] + corr_sh[2][j];
    }
    float im1 = a2[0];
    #pragma unroll
    for (int j=1;j<16;j++) im1 = fmaxf(im1, a2[j]);

    float im2 = nm;
    if (tid < 2){
      float a3[16];
      if (tid == 0){
        #pragma unroll
        for (int j=0;j<16;j++)
          a3[j] = kb[j] + wsum[0*16+j]*x_sh[254] + wsum[1*16+j]*x_sh[255]
                + corr_sh[3][j] + corr_sh[4][j] + corr_sh[5][j];
      } else {
        #pragma unroll
        for (int j=0;j<16;j++)
          a3[j] = kb[j] + wsum[0*16+j]*x_sh[255]
                + corr_sh[6][j] + corr_sh[7][j] + corr_sh[8][j] + corr_sh[9][j];
      }
      im2 = a3[0];
      #pragma unroll
      for (int j=1;j<16;j++) im2 = fmaxf(im2, a3[j]);
    }

    float x1v = ws[WS_C1B];
    #pragma unroll
    for (int t=0;t<3;++t){
      int pos = tid + t - 1;
      float v = x_sh[pos & 255];
      v = (pos>=0 && pos<256) ? v : 0.f;
      x1v = fmaf(v, ws[WS_C1W+t], x1v);
    }

    in_sh[r][1 + tid]   = x1v;
    in_sh[r][257 + tid] = im1;
    in_sh[r][513 + tid] = im2;
    in_sh[r][769 + tid] = nm;
  }
  __syncthreads();

  const float* W12 = ws + WS_W12;
  float b12v = ws[WS_B12 + tid];
  float z[ROWS];
  #pragma unroll
  for (int r=0;r<ROWS;r++) z[r] = b12v;
  for (int c=0; c<1024; c+=4){
    float w0 = W12[(size_t)(c+0)*256 + tid];
    float w1v = W12[(size_t)(c+1)*256 + tid];
    float w2v = W12[(size_t)(c+2)*256 + tid];
    float w3v_ = W12[(size_t)(c+3)*256 + tid];
    #pragma unroll
    for (int r=0;r<ROWS;r++){
      float4 iv = *(const float4*)&in_sh[r][c];
      z[r] = fmaf(iv.x, w0, z[r]);
      z[r] = fmaf(iv.y, w1v, z[r]);
      z[r] = fmaf(iv.z, w2v, z[r]);
      z[r] = fmaf(iv.w, w3v_, z[r]);
    }
  }
  {
    float wl = W12[(size_t)1024*256 + tid];
    #pragma unroll
    for (int r=0;r<ROWS;r++) z[r] = fmaf(in_sh[r][1024], wl, z[r]);
  }

  float w3v = w3[tid];
  #pragma unroll
  for (int r=0;r<ROWS;r++){
    float p = fmaxf(z[r], 0.f) * w3v;
    #pragma unroll
    for (int off=32; off; off>>=1) p += __shfl_xor(p, off, 64);
    if ((tid&63)==0) red_sh[r][tid>>6] = p;
  }
  __syncthreads();
  if (tid < ROWS){
    float s = red_sh[tid][0]+red_sh[tid][1]+red_sh[tid][2]+red_sh[tid][3] + b3[0];
    float x3 = fmaxf(s, 0.f);
    out0[n0 + tid] = pred_s[tid] + x3;
  }
}

extern "C" void kernel_launch(void* const* d_in, const int* in_sizes, int n_in,
                              void* d_out, int out_size, void* d_ws, size_t ws_size,
                              hipStream_t stream){
  const float* X    = (const float*)d_in[0];
  const float* Xtr  = (const float*)d_in[1];
  const float* ytr  = (const float*)d_in[2];
  const float* nd   = (const float*)d_in[3];
  const float* mtr  = (const float*)d_in[4];
  const float* mb   = (const float*)d_in[5];
  const float* Watt = (const float*)d_in[6];
  const float* asrc = (const float*)d_in[7];
  const float* adst = (const float*)d_in[8];
  const float* w1   = (const float*)d_in[9];
  const float* b1   = (const float*)d_in[10];
  const float* w2   = (const float*)d_in[11];
  const float* b2   = (const float*)d_in[12];
  const float* w3   = (const float*)d_in[13];
  const float* b3   = (const float*)d_in[14];
  const float* c1w  = (const float*)d_in[15];
  const float* c1b  = (const float*)d_in[16];
  const float* ckw  = (const float*)d_in[17];
  const float* ckb  = (const float*)d_in[18];
  const int* nind = (const int*)d_in[19];
  float* ws = (float*)d_ws;
  float* out0 = (float*)d_out;
  float* outA = out0 + NO;
  float* outB = out0 + NO + NO*KNN;

  k0_prep<<<dim3(4), dim3(256), 0, stream>>>(Watt, asrc, adst, b1, w2, b2, c1w, c1b, ckw, ckb, ws);
  k1_fold<<<dim3(65), dim3(256), 0, stream>>>(w1, w2, ws + WS_W12);
  if (ws_size >= WS_NEED_BYTES){
    k2a_stage<<<dim3(NO), dim3(256), 0, stream>>>(X, Xtr, ytr, nd, mtr, mb, nind,
                                                  (const float*)ws, ws + WS_INA, outA, outB);
    k2b_mlp<<<dim3(NO/16), dim3(256), 0, stream>>>((const float*)ws, w3, b3, out0);
  } else {
    k2_fused<<<dim3(NO/ROWS), dim3(256), 0, stream>>>(X, Xtr, ytr, nd, mtr, mb, nind,
                                                      (const float*)ws, w3, b3,
                                                      out0, outA, outB);
  }
}

// Round 6
// 233.520 us; speedup vs baseline: 1.5598x; 1.0359x over previous
//
#include <hip/hip_runtime.h>

#define NO 8192
#define NTRAIN 100000
#define DIM 256
#define KNN 16
#define ROWS 8

// ws layout (float offsets)
#define WS_VSRC 0
#define WS_VDST 256
#define WS_B12  512
#define WS_WCONV 768        // [ci][t][co] : (ci*5+t)*16+co, 1280 floats
#define WS_WSUM 2048        // [t][co] : t*16+co, 80 floats
#define WS_KB   2128        // 16
#define WS_C1W  2144        // 3
#define WS_C1B  2147        // 1
#define WS_WB   2176        // bf16 MFMA B-frags: [3][64][8] u16 = 1536 u16 = 768 floats
#define WS_W12  4096        // [1040][256] floats (rows >=1025 zeroed) = 266240
#define WS_INA  270336      // [8192][1040] floats = 8519680
#define WS_NEED_BYTES ((size_t)(WS_INA + (size_t)NO*1040) * 4)

typedef unsigned int u32;
typedef unsigned short u16;
typedef __attribute__((ext_vector_type(8))) short bf16x8;
typedef __attribute__((ext_vector_type(4))) float f32x4;

__device__ __forceinline__ u16 f2bf(float f){
  u32 u = __float_as_uint(f);
  u32 r = (u + 0x7FFFu + ((u>>16)&1u)) >> 16;
  return (u16)r;
}
__device__ __forceinline__ float bf2f(u16 v){ return __uint_as_float(((u32)v)<<16); }

// ---------------- K0: small precomputes ----------------
__global__ __launch_bounds__(256) void k0_prep(
    const float* __restrict__ Watt, const float* __restrict__ asrc, const float* __restrict__ adst,
    const float* __restrict__ b1, const float* __restrict__ w2, const float* __restrict__ b2,
    const float* __restrict__ c1w, const float* __restrict__ c1b,
    const float* __restrict__ ckw, const float* __restrict__ ckb,
    float* __restrict__ ws){
  int tid = threadIdx.x;
  int b = blockIdx.x;
  if (b < 2){
    __shared__ float a_sh[256];
    const float* av = (b==0) ? asrc : adst;
    a_sh[tid] = av[tid];
    __syncthreads();
    const float4* wp = (const float4*)(Watt + tid*DIM);
    float s = 0.f;
    for (int i=0;i<DIM/4;i++){
      float4 u = wp[i];
      int o = i*4;
      s += u.x*a_sh[o+0] + u.y*a_sh[o+1] + u.z*a_sh[o+2] + u.w*a_sh[o+3];
    }
    ws[(b==0?WS_VSRC:WS_VDST) + tid] = s;
  } else if (b == 2){
    float s = b2[tid];
    for (int h=0; h<512; ++h) s += b1[h] * w2[h*256+tid];
    ws[WS_B12+tid] = s;
  } else {
    for (int idx=tid; idx<1280; idx+=256){
      int co = idx/80, r = idx%80; int ci = r/5, t = r%5;
      ws[WS_WCONV + (ci*5+t)*16 + co] = ckw[idx];
    }
    // bf16 B-fragments for the conv MFMA: wb[s][lane][j]
    // (g,j) -> k convention: g=lane>>4, n=lane&15, ci=8*(g&1)+j, t=2*s+(g>>1)
    {
      u16* wb = (u16*)(ws + WS_WB);
      for (int e = tid; e < 1536; e += 256){
        int s = e >> 9, rem = e & 511, lane = rem >> 3, j = rem & 7;
        int g = lane >> 4, n = lane & 15;
        int ci = 8*(g&1) + j, t = 2*s + (g>>1);
        float v = (t < 5) ? ckw[n*80 + ci*5 + t] : 0.f;
        wb[e] = f2bf(v);
      }
    }
    __syncthreads();
    if (tid < 80){
      int t = tid/16, co = tid%16;
      float s = 0.f;
      for (int ci=0;ci<16;ci++) s += ws[WS_WCONV + (ci*5+t)*16 + co];
      ws[WS_WSUM + t*16 + co] = s;
    }
    if (tid < 16) ws[WS_KB + tid] = ckb[tid];
    if (tid < 3)  ws[WS_C1W + tid] = c1w[tid];
    if (tid == 3) ws[WS_C1B] = c1b[0];
  }
}

// ---------------- K1: fold W12 = w1 @ w2  ([1040][256], rows>=1025 zero) ----------------
__global__ __launch_bounds__(256) void k1_fold(
    const float* __restrict__ w1, const float* __restrict__ w2, float* __restrict__ w12){
  __shared__ float aT[16][20];
  int tid = threadIdx.x;
  int r0 = blockIdx.x * 16;
  float acc[16];
  #pragma unroll
  for (int j=0;j<16;j++) acc[j] = 0.f;
  int kk = tid & 15, rr = tid >> 4;
  for (int kt=0; kt<32; ++kt){
    int row = r0 + rr;
    float av = (row < 1025) ? w1[row*512 + kt*16 + kk] : 0.f;
    __syncthreads();
    aT[kk][rr] = av;
    __syncthreads();
    #pragma unroll
    for (int k=0;k<16;++k){
      float bv = w2[(kt*16+k)*256 + tid];
      const float* a = aT[k];
      #pragma unroll
      for (int j=0;j<16;j++) acc[j] = fmaf(a[j], bv, acc[j]);
    }
  }
  #pragma unroll
  for (int j=0;j<16;j++){
    int row = r0 + j;
    w12[(size_t)row*256 + tid] = (row < 1025) ? acc[j] : 0.f;
  }
}

// ---------------- K2a: stage-1, one row per block, MFMA conv ----------------
__global__ __launch_bounds__(256) void k2a_stage(
    const float* __restrict__ X, const float* __restrict__ Xtr, const float* __restrict__ ytr,
    const float* __restrict__ ndist, const float* __restrict__ mtr, const float* __restrict__ mb,
    const int* __restrict__ nind,
    const float* __restrict__ ws, float* __restrict__ inA,
    float* __restrict__ outA, float* __restrict__ outB){
  __shared__ float x_sh[256];
  __shared__ float cand_sh[16][256];
  __shared__ __align__(16) short candT[262][24];   // [pos+2][ci], bf16, 48B rows
  __shared__ __align__(16) float nm_sh[256];
  __shared__ float corr_sh[10][16];
  __shared__ float wgt_sh[16];
  __shared__ int   idx_sh[16];
  __shared__ float red_sh[4];
  __shared__ float hx_sh, pred_sh;
  __shared__ float hc_sh[16];

  int n = blockIdx.x;
  int tid = threadIdx.x;
  const float* vsrc = ws + WS_VSRC;
  const float* vdst = ws + WS_VDST;
  const float* wcv  = ws + WS_WCONV;
  const float* wsum = ws + WS_WSUM;
  const float* kb   = ws + WS_KB;

  float xv = X[n*256+tid];
  x_sh[tid] = xv;
  float xm = xv * mb[n*256+tid];
  float part = xm * vsrc[tid];
  #pragma unroll
  for (int off=32; off; off>>=1) part += __shfl_xor(part, off, 64);
  if ((tid&63)==0) red_sh[tid>>6] = part;
  __syncthreads();
  if (tid==0) hx_sh = red_sh[0]+red_sh[1]+red_sh[2]+red_sh[3];
  if (tid<16){
    int j = nind[n*16+tid];
    idx_sh[tid] = j;
    float d = ndist[n*16+tid];
    float inv = 1.f/(d + 1e-8f);
    float s = inv;
    #pragma unroll
    for (int off=8; off; off>>=1) s += __shfl_xor(s, off, 16);
    float w = inv/s;
    wgt_sh[tid] = w;
    float pp = ytr[j] * w;
    #pragma unroll
    for (int off=8; off; off>>=1) pp += __shfl_xor(pp, off, 16);
    if (tid==0) pred_sh = pp;
  }
  __syncthreads();
  // gather candidates (float4), raw (unweighted)
  {
    int kk4 = tid >> 6;
    int c4 = (tid & 63) * 4;
    #pragma unroll
    for (int g=0; g<4; ++g){
      int k = g*4 + kk4;
      size_t basei = (size_t)idx_sh[k]*256 + c4;
      float4 xv4 = *(const float4*)(Xtr + basei);
      float4 mv4 = *(const float4*)(mtr + basei);
      float4 cv;
      cv.x = xv4.x*mv4.x; cv.y = xv4.y*mv4.y; cv.z = xv4.z*mv4.z; cv.w = xv4.w*mv4.w;
      *(float4*)&cand_sh[k][c4] = cv;
    }
  }
  __syncthreads();
  // h_c from RAW cand : 16 groups of 16 threads
  {
    int k = tid>>4, d0 = tid&15;
    float s = 0.f;
    #pragma unroll
    for (int i=0;i<16;i++){ int d = d0 + i*16; s += cand_sh[k][d]*vdst[d]; }
    #pragma unroll
    for (int off=8; off; off>>=1) s += __shfl_xor(s, off, 16);
    if (d0==0) hc_sh[k] = s;
  }
  // candT build: weighted, bf16; thread tid -> row 2+tid
  {
    u32 packed[8];
    #pragma unroll
    for (int q=0;q<8;q++){
      float v0 = cand_sh[2*q][tid]   * wgt_sh[2*q];
      float v1 = cand_sh[2*q+1][tid] * wgt_sh[2*q+1];
      packed[q] = (u32)f2bf(v0) | ((u32)f2bf(v1) << 16);
    }
    u32* dst = (u32*)&candT[2+tid][0];
    #pragma unroll
    for (int q=0;q<8;q++) dst[q] = packed[q];
  }
  if (tid < 6){
    int r = (tid < 2) ? tid : 256 + tid;  // rows 0,1,258..261
    u32* dst = (u32*)&candT[r][0];
    #pragma unroll
    for (int q=0;q<12;q++) dst[q] = 0;
  }
  __syncthreads();
  // attention outputs
  if (tid<16){
    float e = hx_sh + hc_sh[tid];
    e = (e>=0.f) ? e : 0.2f*e;
    outB[n*16+tid] = e;
    float m = e;
    #pragma unroll
    for (int off=8; off; off>>=1) m = fmaxf(m, __shfl_xor(m, off, 16));
    float ex = __expf(e - m);
    float ssum = ex;
    #pragma unroll
    for (int off=8; off; off>>=1) ssum += __shfl_xor(ssum, off, 16);
    outA[n*16+tid] = ex/ssum;
  }
  // corrections from candT (weighted bf16 values)
  if (tid < 160){
    const int tt[10] = {4,3,4,2,3,4,1,2,3,4};
    const int pp[10] = {0,0,1,0,1,2,0,1,2,3};
    int pair = tid >> 4, co = tid & 15;
    int t = tt[pair], p = pp[pair];
    float s = 0.f;
    #pragma unroll
    for (int ci=0; ci<16; ++ci)
      s += wcv[(ci*5+t)*16+co] * bf2f((u16)candT[2+p][ci]);
    corr_sh[pair][co] = s;
  }
  // Inter first half via wsum (x zero-padded); corr added post-sync for l>=254
  float a2[16];
  #pragma unroll
  for (int j=0;j<16;j++) a2[j] = kb[j];
  #pragma unroll
  for (int t=0;t<5;++t){
    int pos = tid + t - 2;
    float v = x_sh[pos & 255];
    v = (pos >= 0 && pos < 256) ? v : 0.f;
    const float* wb_ = wsum + t*16;
    #pragma unroll
    for (int j=0;j<16;j++) a2[j] = fmaf(v, wb_[j], a2[j]);
  }
  // X1: 3-tap conv of raw X
  float x1v = ws[WS_C1B];
  #pragma unroll
  for (int t=0;t<3;++t){
    int pos = tid + t - 1;
    float v = x_sh[pos & 255];
    v = (pos>=0 && pos<256) ? v : 0.f;
    x1v = fmaf(v, ws[WS_C1W+t], x1v);
  }

  // ---- Neighbors conv via MFMA: P[l][co], M=256 N=16 K=80(pad 96) ----
  {
    int wave = tid >> 6;
    int lane = tid & 63;
    int g    = lane >> 4;
    int lm   = lane & 15;        // A-row within tile / C-col (=co)
    int colh = g & 1;            // which 8-ci half
    int tg   = g >> 1;           // tap offset within pair
    const u16* wb = (const u16*)(ws + WS_WB);
    bf16x8 bfr0 = *(const bf16x8*)(wb + 0*512 + lane*8);
    bf16x8 bfr1 = *(const bf16x8*)(wb + 1*512 + lane*8);
    bf16x8 bfr2 = *(const bf16x8*)(wb + 2*512 + lane*8);
    float kbv = kb[lm];
    #pragma unroll
    for (int i=0;i<4;i++){
      int m0 = (wave*4 + i) * 16;
      f32x4 a = {kbv, kbv, kbv, kbv};
      int rbase = m0 + lm + tg;
      bf16x8 af0 = *(const bf16x8*)&candT[rbase + 0][8*colh];
      a = __builtin_amdgcn_mfma_f32_16x16x32_bf16(af0, bfr0, a, 0,0,0);
      bf16x8 af1 = *(const bf16x8*)&candT[rbase + 2][8*colh];
      a = __builtin_amdgcn_mfma_f32_16x16x32_bf16(af1, bfr1, a, 0,0,0);
      bf16x8 af2 = *(const bf16x8*)&candT[rbase + 4][8*colh];
      a = __builtin_amdgcn_mfma_f32_16x16x32_bf16(af2, bfr2, a, 0,0,0);
      // max over co (= lanes differing in low 4 bits)
      #pragma unroll
      for (int off=1; off<16; off<<=1){
        #pragma unroll
        for (int r=0;r<4;r++){
          float o = __shfl_xor(a[r], off, 64);
          a[r] = fmaxf(a[r], o);
        }
      }
      if (lm == 0){
        float4 st; st.x=a[0]; st.y=a[1]; st.z=a[2]; st.w=a[3];
        *(float4*)&nm_sh[m0 + g*4] = st;   // rows m0+4g .. +3
      }
    }
  }
  __syncthreads();

  float nm = nm_sh[tid];
  if (tid == 254){
    #pragma unroll
    for (int j=0;j<16;j++) a2[j] += corr_sh[0][j];
  }
  if (tid == 255){
    #pragma unroll
    for (int j=0;j<16;j++) a2[j] += corr_sh[1][j] + corr_sh[2][j];
  }
  float im1 = a2[0];
  #pragma unroll
  for (int j=1;j<16;j++) im1 = fmaxf(im1, a2[j]);

  float im2 = nm;
  if (tid < 2){
    float a3[16];
    if (tid == 0){
      #pragma unroll
      for (int j=0;j<16;j++)
        a3[j] = kb[j] + wsum[0*16+j]*x_sh[254] + wsum[1*16+j]*x_sh[255]
              + corr_sh[3][j] + corr_sh[4][j] + corr_sh[5][j];
    } else {
      #pragma unroll
      for (int j=0;j<16;j++)
        a3[j] = kb[j] + wsum[0*16+j]*x_sh[255]
              + corr_sh[6][j] + corr_sh[7][j] + corr_sh[8][j] + corr_sh[9][j];
    }
    im2 = a3[0];
    #pragma unroll
    for (int j=1;j<16;j++) im2 = fmaxf(im2, a3[j]);
  }

  size_t base = (size_t)n*1040;
  inA[base + 1 + tid]   = x1v;
  inA[base + 257 + tid] = im1;
  inA[base + 513 + tid] = im2;
  inA[base + 769 + tid] = nm;
  if (tid == 0) inA[base] = pred_sh;
  if (tid < 15) inA[base + 1025 + tid] = 0.f;
}

// ---------------- K2b: GEMM inputs[8192x1040] @ W12[1040x256] + epilogue ----------------
__global__ __launch_bounds__(256) void k2b_mlp(
    const float* __restrict__ ws, const float* __restrict__ w3, const float* __restrict__ b3,
    float* __restrict__ out0){
  __shared__ float aT[16][20];
  __shared__ float red[16][4];
  int tid = threadIdx.x;
  int r0 = blockIdx.x * 16;
  const float* W12 = ws + WS_W12;
  const float* inA = ws + WS_INA;
  float b12v = ws[WS_B12 + tid];
  float acc[16];
  #pragma unroll
  for (int j=0;j<16;j++) acc[j] = b12v;
  int kk = tid & 15, rr = tid >> 4;
  for (int kt=0; kt<65; ++kt){
    float av = inA[(size_t)(r0+rr)*1040 + kt*16 + kk];
    __syncthreads();
    aT[kk][rr] = av;
    __syncthreads();
    #pragma unroll
    for (int k=0;k<16;++k){
      float bv = W12[(size_t)(kt*16+k)*256 + tid];
      const float* a = aT[k];
      #pragma unroll
      for (int j=0;j<16;j++) acc[j] = fmaf(a[j], bv, acc[j]);
    }
  }
  float w3v = w3[tid];
  #pragma unroll
  for (int j=0;j<16;j++){
    float p = fmaxf(acc[j], 0.f) * w3v;
    #pragma unroll
    for (int off=32; off; off>>=1) p += __shfl_xor(p, off, 64);
    if ((tid&63)==0) red[j][tid>>6] = p;
  }
  __syncthreads();
  if (tid < 16){
    float s = red[tid][0]+red[tid][1]+red[tid][2]+red[tid][3] + b3[0];
    float x3 = fmaxf(s, 0.f);
    out0[r0+tid] = inA[(size_t)(r0+tid)*1040] + x3;
  }
}

// ---------------- Fallback: fused (round-4) path, used only if ws too small ----------------
__global__ __launch_bounds__(256) void k2_fused(
    const float* __restrict__ X, const float* __restrict__ Xtr, const float* __restrict__ ytr,
    const float* __restrict__ ndist, const float* __restrict__ mtr, const float* __restrict__ mb,
    const int* __restrict__ nind,
    const float* __restrict__ ws,
    const float* __restrict__ w3, const float* __restrict__ b3,
    float* __restrict__ out0, float* __restrict__ outA, float* __restrict__ outB){
  __shared__ float x_sh[256];
  __shared__ float cand_sh[16][256];
  __shared__ __align__(16) float in_sh[ROWS][1028];
  __shared__ float corr_sh[10][16];
  __shared__ float wgt_sh[16];
  __shared__ int   idx_sh[16];
  __shared__ float red_sh[ROWS][4];
  __shared__ float hx_sh;
  __shared__ float pred_s[ROWS];
  __shared__ float hc_sh[16];

  int n0 = blockIdx.x * ROWS;
  int tid = threadIdx.x;
  const float* vsrc = ws + WS_VSRC;
  const float* vdst = ws + WS_VDST;
  const float* wcv  = ws + WS_WCONV;
  const float* wsum = ws + WS_WSUM;
  const float* kb   = ws + WS_KB;

  for (int r = 0; r < ROWS; ++r){
    int n = n0 + r;
    __syncthreads();

    float xv = X[n*256+tid];
    x_sh[tid] = xv;
    float xm = xv * mb[n*256+tid];
    float part = xm * vsrc[tid];
    #pragma unroll
    for (int off=32; off; off>>=1) part += __shfl_xor(part, off, 64);
    if ((tid&63)==0) red_sh[0][tid>>6] = part;
    __syncthreads();
    if (tid==0) hx_sh = red_sh[0][0]+red_sh[0][1]+red_sh[0][2]+red_sh[0][3];
    if (tid<16){
      int j = nind[n*16+tid];
      idx_sh[tid] = j;
      float d = ndist[n*16+tid];
      float inv = 1.f/(d + 1e-8f);
      float s = inv;
      #pragma unroll
      for (int off=8; off; off>>=1) s += __shfl_xor(s, off, 16);
      float w = inv/s;
      wgt_sh[tid] = w;
      float pp = ytr[j] * w;
      #pragma unroll
      for (int off=8; off; off>>=1) pp += __shfl_xor(pp, off, 16);
      if (tid==0){ pred_s[r] = pp; in_sh[r][0] = pp; }
    }
    __syncthreads();
    {
      int kk4 = tid >> 6;
      int c4 = (tid & 63) * 4;
      #pragma unroll
      for (int g=0; g<4; ++g){
        int k = g*4 + kk4;
        size_t basei = (size_t)idx_sh[k]*256 + c4;
        float4 xv4 = *(const float4*)(Xtr + basei);
        float4 mv4 = *(const float4*)(mtr + basei);
        float4 cv;
        cv.x = xv4.x*mv4.x; cv.y = xv4.y*mv4.y; cv.z = xv4.z*mv4.z; cv.w = xv4.w*mv4.w;
        *(float4*)&cand_sh[k][c4] = cv;
      }
    }
    __syncthreads();
    {
      int k = tid>>4, d0 = tid&15;
      float s = 0.f;
      #pragma unroll
      for (int i=0;i<16;i++){ int d = d0 + i*16; s += cand_sh[k][d]*vdst[d]; }
      #pragma unroll
      for (int off=8; off; off>>=1) s += __shfl_xor(s, off, 16);
      if (d0==0) hc_sh[k] = s;
    }
    __syncthreads();
    if (tid<16){
      float e = hx_sh + hc_sh[tid];
      e = (e>=0.f) ? e : 0.2f*e;
      outB[n*16+tid] = e;
      float m = e;
      #pragma unroll
      for (int off=8; off; off>>=1) m = fmaxf(m, __shfl_xor(m, off, 16));
      float ex = __expf(e - m);
      float ssum = ex;
      #pragma unroll
      for (int off=8; off; off>>=1) ssum += __shfl_xor(ssum, off, 16);
      outA[n*16+tid] = ex/ssum;
    }
    #pragma unroll
    for (int k=0;k<16;k++) cand_sh[k][tid] *= wgt_sh[k];
    __syncthreads();

    if (tid < 160){
      const int tt[10] = {4,3,4,2,3,4,1,2,3,4};
      const int pp[10] = {0,0,1,0,1,2,0,1,2,3};
      int pair = tid >> 4, co = tid & 15;
      int t = tt[pair], p = pp[pair];
      float s = 0.f;
      #pragma unroll
      for (int ci=0; ci<16; ++ci) s += wcv[(ci*5+t)*16+co] * cand_sh[ci][p];
      corr_sh[pair][co] = s;
    }

    float acc[16];
    #pragma unroll
    for (int j=0;j<16;j++) acc[j] = kb[j];
    for (int ci=0; ci<16; ++ci){
      const float* wci = wcv + ci*80;
      #pragma unroll
      for (int t=0;t<5;++t){
        int pos = tid + t - 2;
        float v = cand_sh[ci][pos & 255];
        v = (pos >= 0 && pos < 256) ? v : 0.f;
        const float* wb_ = wci + t*16;
        #pragma unroll
        for (int j=0;j<16;j++) acc[j] = fmaf(v, wb_[j], acc[j]);
      }
    }
    float nm = acc[0];
    #pragma unroll
    for (int j=1;j<16;j++) nm = fmaxf(nm, acc[j]);

    float a2[16];
    #pragma unroll
    for (int j=0;j<16;j++) a2[j] = kb[j];
    #pragma unroll
    for (int t=0;t<5;++t){
      int pos = tid + t - 2;
      float v = x_sh[pos & 255];
      v = (pos >= 0 && pos < 256) ? v : 0.f;
      const float* wb_ = wsum + t*16;
      #pragma unroll
      for (int j=0;j<16;j++) a2[j] = fmaf(v, wb_[j], a2[j]);
    }
    __syncthreads();
    if (tid == 254){
      #pragma unroll
      for (int j=0;j<16;j++) a2[j] += corr_sh[0][j];
    }
    if (tid == 255){
      #pragma unroll
      for (int j=0;j<16;j++) a2[j] += corr_sh[1][j] + corr_sh[2][j];
    }
    float im1 = a2[0];
    #pragma unroll
    for (int j=1;j<16;j++) im1 = fmaxf(im1, a2[j]);

    float im2 = nm;
    if (tid < 2){
      float a3[16];
      if (tid == 0){
        #pragma unroll
        for (int j=0;j<16;j++)
          a3[j] = kb[j] + wsum[0*16+j]*x_sh[254] + wsum[1*16+j]*x_sh[255]
                + corr_sh[3][j] + corr_sh[4][j] + corr_sh[5][j];
      } else {
        #pragma unroll
        for (int j=0;j<16;j++)
          a3[j] = kb[j] + wsum[0*16+j]*x_sh[255]
                + corr_sh[6][j] + corr_sh[7][j] + corr_sh[8][j] + corr_sh[9][j];
      }
      im2 = a3[0];
      #pragma unroll
      for (int j=1;j<16;j++) im2 = fmaxf(im2, a3[j]);
    }

    float x1v = ws[WS_C1B];
    #pragma unroll
    for (int t=0;t<3;++t){
      int pos = tid + t - 1;
      float v = x_sh[pos & 255];
      v = (pos>=0 && pos<256) ? v : 0.f;
      x1v = fmaf(v, ws[WS_C1W+t], x1v);
    }

    in_sh[r][1 + tid]   = x1v;
    in_sh[r][257 + tid] = im1;
    in_sh[r][513 + tid] = im2;
    in_sh[r][769 + tid] = nm;
  }
  __syncthreads();

  const float* W12 = ws + WS_W12;
  float b12v = ws[WS_B12 + tid];
  float z[ROWS];
  #pragma unroll
  for (int r=0;r<ROWS;r++) z[r] = b12v;
  for (int c=0; c<1024; c+=4){
    float w0 = W12[(size_t)(c+0)*256 + tid];
    float w1v = W12[(size_t)(c+1)*256 + tid];
    float w2v = W12[(size_t)(c+2)*256 + tid];
    float w3v_ = W12[(size_t)(c+3)*256 + tid];
    #pragma unroll
    for (int r=0;r<ROWS;r++){
      float4 iv = *(const float4*)&in_sh[r][c];
      z[r] = fmaf(iv.x, w0, z[r]);
      z[r] = fmaf(iv.y, w1v, z[r]);
      z[r] = fmaf(iv.z, w2v, z[r]);
      z[r] = fmaf(iv.w, w3v_, z[r]);
    }
  }
  {
    float wl = W12[(size_t)1024*256 + tid];
    #pragma unroll
    for (int r=0;r<ROWS;r++) z[r] = fmaf(in_sh[r][1024], wl, z[r]);
  }

  float w3v = w3[tid];
  #pragma unroll
  for (int r=0;r<ROWS;r++){
    float p = fmaxf(z[r], 0.f) * w3v;
    #pragma unroll
    for (int off=32; off; off>>=1) p += __shfl_xor(p, off, 64);
    if ((tid&63)==0) red_sh[r][tid>>6] = p;
  }
  __syncthreads();
  if (tid < ROWS){
    float s = red_sh[tid][0]+red_sh[tid][1]+red_sh[tid][2]+red_sh[tid][3] + b3[0];
    float x3 = fmaxf(s, 0.f);
    out0[n0 + tid] = pred_s[tid] + x3;
  }
}

extern "C" void kernel_launch(void* const* d_in, const int* in_sizes, int n_in,
                              void* d_out, int out_size, void* d_ws, size_t ws_size,
                              hipStream_t stream){
  const float* X    = (const float*)d_in[0];
  const float* Xtr  = (const float*)d_in[1];
  const float* ytr  = (const float*)d_in[2];
  const float* nd   = (const float*)d_in[3];
  const float* mtr  = (const float*)d_in[4];
  const float* mb   = (const float*)d_in[5];
  const float* Watt = (const float*)d_in[6];
  const float* asrc = (const float*)d_in[7];
  const float* adst = (const float*)d_in[8];
  const float* w1   = (const float*)d_in[9];
  const float* b1   = (const float*)d_in[10];
  const float* w2   = (const float*)d_in[11];
  const float* b2   = (const float*)d_in[12];
  const float* w3   = (const float*)d_in[13];
  const float* b3   = (const float*)d_in[14];
  const float* c1w  = (const float*)d_in[15];
  const float* c1b  = (const float*)d_in[16];
  const float* ckw  = (const float*)d_in[17];
  const float* ckb  = (const float*)d_in[18];
  const int* nind = (const int*)d_in[19];
  float* ws = (float*)d_ws;
  float* out0 = (float*)d_out;
  float* outA = out0 + NO;
  float* outB = out0 + NO + NO*KNN;

  k0_prep<<<dim3(4), dim3(256), 0, stream>>>(Watt, asrc, adst, b1, w2, b2, c1w, c1b, ckw, ckb, ws);
  k1_fold<<<dim3(65), dim3(256), 0, stream>>>(w1, w2, ws + WS_W12);
  if (ws_size >= WS_NEED_BYTES){
    k2a_stage<<<dim3(NO), dim3(256), 0, stream>>>(X, Xtr, ytr, nd, mtr, mb, nind,
                                                  (const float*)ws, ws + WS_INA, outA, outB);
    k2b_mlp<<<dim3(NO/16), dim3(256), 0, stream>>>((const float*)ws, w3, b3, out0);
  } else {
    k2_fused<<<dim3(NO/ROWS), dim3(256), 0, stream>>>(X, Xtr, ytr, nd, mtr, mb, nind,
                                                      (const float*)ws, w3, b3,
                                                      out0, outA, outB);
  }
}

// Round 8
// 155.275 us; speedup vs baseline: 2.3458x; 1.5039x over previous
//
#include <hip/hip_runtime.h>

#define NO 8192
#define NTRAIN 100000
#define DIM 256
#define KNN 16
#define ROWS 8
#define KPAD 1088

// ws layout (float offsets)
#define WS_VSRC 0
#define WS_VDST 256
#define WS_B12  512
#define WS_WCONV 768        // [ci][t][co] f32, 1280
#define WS_WSUM 2048        // [t][co] f32, 80
#define WS_KB   2128        // 16
#define WS_C1W  2144        // 3
#define WS_C1B  2147        // 1
#define WS_WB   2176        // conv MFMA B-frags [3][64][8] u16
#define WS_W12  4096        // f32 [1040][256] (fallback path)
#define WS_W12T 270336      // u16 [256][1088]
#define WS_PRED 409600      // f32 [8192]
#define WS_INBF 417792      // u16 [8192][1088]
#define WS_END  (417792 + 4456448)
#define WS_NEED_BYTES ((size_t)WS_END * 4)

typedef unsigned int u32;
typedef unsigned short u16;
typedef __attribute__((ext_vector_type(8))) short bf16x8;
typedef __attribute__((ext_vector_type(4))) float f32x4;

__device__ __forceinline__ u16 f2bf(float f){
  u32 u = __float_as_uint(f);
  u32 r = (u + 0x7FFFu + ((u>>16)&1u)) >> 16;
  return (u16)r;
}
__device__ __forceinline__ float bf2f(u16 v){ return __uint_as_float(((u32)v)<<16); }

// ---------------- K0: small precomputes ----------------
__global__ __launch_bounds__(256) void k0_prep(
    const float* __restrict__ Watt, const float* __restrict__ asrc, const float* __restrict__ adst,
    const float* __restrict__ b1, const float* __restrict__ w2, const float* __restrict__ b2,
    const float* __restrict__ c1w, const float* __restrict__ c1b,
    const float* __restrict__ ckw, const float* __restrict__ ckb,
    float* __restrict__ ws){
  int tid = threadIdx.x;
  int b = blockIdx.x;
  if (b < 2){
    __shared__ float a_sh[256];
    const float* av = (b==0) ? asrc : adst;
    a_sh[tid] = av[tid];
    __syncthreads();
    const float4* wp = (const float4*)(Watt + tid*DIM);
    float s = 0.f;
    for (int i=0;i<DIM/4;i++){
      float4 u = wp[i];
      int o = i*4;
      s += u.x*a_sh[o+0] + u.y*a_sh[o+1] + u.z*a_sh[o+2] + u.w*a_sh[o+3];
    }
    ws[(b==0?WS_VSRC:WS_VDST) + tid] = s;
  } else if (b == 2){
    float s = b2[tid];
    for (int h=0; h<512; ++h) s += b1[h] * w2[h*256+tid];
    ws[WS_B12+tid] = s;
  } else {
    for (int idx=tid; idx<1280; idx+=256){
      int co = idx/80, r = idx%80; int ci = r/5, t = r%5;
      ws[WS_WCONV + (ci*5+t)*16 + co] = ckw[idx];
    }
    // conv MFMA B-frags: (g,j)->k convention: ci=8*(g&1)+j, t=2*s+(g>>1)
    {
      u16* wb = (u16*)(ws + WS_WB);
      for (int e = tid; e < 1536; e += 256){
        int s = e >> 9, rem = e & 511, lane = rem >> 3, j = rem & 7;
        int g = lane >> 4, n = lane & 15;
        int ci = 8*(g&1) + j, t = 2*s + (g>>1);
        float v = (t < 5) ? ckw[n*80 + ci*5 + t] : 0.f;
        wb[e] = f2bf(v);
      }
    }
    __syncthreads();
    if (tid < 80){
      int t = tid/16, co = tid%16;
      float s = 0.f;
      for (int ci=0;ci<16;ci++) s += ws[WS_WCONV + (ci*5+t)*16 + co];
      ws[WS_WSUM + t*16 + co] = s;
    }
    if (tid < 16) ws[WS_KB + tid] = ckb[tid];
    if (tid < 3)  ws[WS_C1W + tid] = c1w[tid];
    if (tid == 3) ws[WS_C1B] = c1b[0];
  }
}

// ---------------- K1: fold W12 = w1 @ w2 ; emit f32 [1040][256] + bf16 transposed [256][1088] ----------------
__global__ __launch_bounds__(256) void k1_fold(
    const float* __restrict__ w1, const float* __restrict__ w2, float* __restrict__ ws){
  __shared__ float aT[16][20];
  __shared__ float t16[16][257];
  float* w12 = ws + WS_W12;
  u16* w12t = (u16*)(ws + WS_W12T);
  int tid = threadIdx.x;
  int r0 = blockIdx.x * 16;        // grid 68 -> rows 0..1087
  float acc[16];
  #pragma unroll
  for (int j=0;j<16;j++) acc[j] = 0.f;
  int kk = tid & 15, rr = tid >> 4;
  for (int kt=0; kt<32; ++kt){
    int row = r0 + rr;
    float av = (row < 1025) ? w1[row*512 + kt*16 + kk] : 0.f;
    __syncthreads();
    aT[kk][rr] = av;
    __syncthreads();
    #pragma unroll
    for (int k=0;k<16;++k){
      float bv = w2[(kt*16+k)*256 + tid];
      const float* a = aT[k];
      #pragma unroll
      for (int j=0;j<16;j++) acc[j] = fmaf(a[j], bv, acc[j]);
    }
  }
  #pragma unroll
  for (int j=0;j<16;j++){
    int row = r0 + j;
    if (row < 1040) w12[(size_t)row*256 + tid] = (row < 1025) ? acc[j] : 0.f;
    t16[j][tid] = (row < 1025) ? acc[j] : 0.f;
  }
  __syncthreads();
  // transposed bf16 store, 16 n-rows per pass
  for (int p=0; p<16; ++p){
    int nn = p*16 + (tid>>4);
    int kl = tid & 15;
    w12t[(size_t)nn*KPAD + r0 + kl] = f2bf(t16[kl][nn]);
  }
}

// ---------------- K2a: stage-1, one row per block, lean LDS ----------------
__global__ __launch_bounds__(256) void k2a_stage(
    const float* __restrict__ X, const float* __restrict__ Xtr, const float* __restrict__ ytr,
    const float* __restrict__ ndist, const float* __restrict__ mtr, const float* __restrict__ mb,
    const int* __restrict__ nind,
    float* __restrict__ ws,
    float* __restrict__ outA, float* __restrict__ outB){
  __shared__ float x_sh[256];
  __shared__ __align__(16) short candT[262][24];   // [pos+2][ci] bf16 weighted
  __shared__ float nm_sh[256];
  __shared__ float corr_sh[10][16];
  __shared__ float wgt_sh[16];
  __shared__ int   idx_sh[16];
  __shared__ float red_sh[4];
  __shared__ float hx_sh, pred_sh;
  __shared__ float hc_sh[16];

  int n = blockIdx.x;
  int tid = threadIdx.x;
  const float* vsrc = ws + WS_VSRC;
  const float* vdst = ws + WS_VDST;
  const float* wcv  = ws + WS_WCONV;
  const float* wsum = ws + WS_WSUM;
  const float* kb   = ws + WS_KB;
  u16* inbf = (u16*)(ws + WS_INBF) + (size_t)n*KPAD;

  // ---- phase A ----
  float xv = X[n*256+tid];
  x_sh[tid] = xv;
  float part = xv * mb[n*256+tid] * vsrc[tid];
  #pragma unroll
  for (int off=32; off; off>>=1) part += __shfl_xor(part, off, 64);
  if ((tid&63)==0) red_sh[tid>>6] = part;
  if (tid<16){
    int j = nind[n*16+tid];
    idx_sh[tid] = j;
    float d = ndist[n*16+tid];
    float inv = 1.f/(d + 1e-8f);
    float s = inv;
    #pragma unroll
    for (int off=8; off; off>>=1) s += __shfl_xor(s, off, 16);
    float w = inv/s;
    wgt_sh[tid] = w;
    float pp = ytr[j] * w;
    #pragma unroll
    for (int off=8; off; off>>=1) pp += __shfl_xor(pp, off, 16);
    if (tid==0) pred_sh = pp;
  }
  __syncthreads();   // B1

  // ---- phase B: gather (transposed) -> weighted bf16 candT ----
  if (tid==0) hx_sh = red_sh[0]+red_sh[1]+red_sh[2]+red_sh[3];
  {
    u32* dst = (u32*)&candT[2+tid][0];
    #pragma unroll
    for (int q=0;q<8;q++){
      int i0 = idx_sh[2*q]*256 + tid;
      int i1 = idx_sh[2*q+1]*256 + tid;
      float v0 = Xtr[i0]*mtr[i0]*wgt_sh[2*q];
      float v1 = Xtr[i1]*mtr[i1]*wgt_sh[2*q+1];
      dst[q] = (u32)f2bf(v0) | ((u32)f2bf(v1) << 16);
    }
  }
  if (tid < 6){
    int r = (tid < 2) ? tid : 256 + tid;  // zero rows 0,1,258..261
    u32* dst = (u32*)&candT[r][0];
    #pragma unroll
    for (int q=0;q<12;q++) dst[q] = 0;
  }
  __syncthreads();   // B2

  // ---- phase C ----
  // h_c from weighted bf16, divided by weight (16 groups of 16)
  {
    int k = tid>>4, d0 = tid&15;
    float s = 0.f;
    #pragma unroll
    for (int i=0;i<16;i++){
      int d = d0 + i*16;
      s += bf2f((u16)candT[2+d][k]) * vdst[d];
    }
    #pragma unroll
    for (int off=8; off; off>>=1) s += __shfl_xor(s, off, 16);
    if (d0==0) hc_sh[k] = s / wgt_sh[k];
  }
  // correction terms from candT
  if (tid < 160){
    const int tt[10] = {4,3,4,2,3,4,1,2,3,4};
    const int pp[10] = {0,0,1,0,1,2,0,1,2,3};
    int pair = tid >> 4, co = tid & 15;
    int t = tt[pair], p = pp[pair];
    float s = 0.f;
    #pragma unroll
    for (int ci=0; ci<16; ++ci)
      s += wcv[(ci*5+t)*16+co] * bf2f((u16)candT[2+p][ci]);
    corr_sh[pair][co] = s;
  }
  // im1 (wsum conv); tid>=254 corrected in phase D
  float im1;
  {
    float a2[16];
    #pragma unroll
    for (int j=0;j<16;j++) a2[j] = kb[j];
    #pragma unroll
    for (int t=0;t<5;++t){
      int pos = tid + t - 2;
      float v = x_sh[pos & 255];
      v = (pos >= 0 && pos < 256) ? v : 0.f;
      const float* wb_ = wsum + t*16;
      #pragma unroll
      for (int j=0;j<16;j++) a2[j] = fmaf(v, wb_[j], a2[j]);
    }
    im1 = a2[0];
    #pragma unroll
    for (int j=1;j<16;j++) im1 = fmaxf(im1, a2[j]);
  }
  // X1
  float x1v = ws[WS_C1B];
  #pragma unroll
  for (int t=0;t<3;++t){
    int pos = tid + t - 1;
    float v = x_sh[pos & 255];
    v = (pos>=0 && pos<256) ? v : 0.f;
    x1v = fmaf(v, ws[WS_C1W+t], x1v);
  }
  // Neighbors conv via MFMA
  {
    int lane = tid & 63, wave = tid >> 6;
    int g    = lane >> 4;
    int lm   = lane & 15;
    int colh = g & 1;
    int tg   = g >> 1;
    const u16* wb = (const u16*)(ws + WS_WB);
    bf16x8 bfr0 = *(const bf16x8*)(wb + 0*512 + lane*8);
    bf16x8 bfr1 = *(const bf16x8*)(wb + 1*512 + lane*8);
    bf16x8 bfr2 = *(const bf16x8*)(wb + 2*512 + lane*8);
    float kbv = kb[lm];
    #pragma unroll
    for (int i=0;i<4;i++){
      int m0 = (wave*4 + i) * 16;
      f32x4 a = {kbv, kbv, kbv, kbv};
      int rbase = m0 + lm + tg;
      bf16x8 af0 = *(const bf16x8*)&candT[rbase + 0][8*colh];
      a = __builtin_amdgcn_mfma_f32_16x16x32_bf16(af0, bfr0, a, 0,0,0);
      bf16x8 af1 = *(const bf16x8*)&candT[rbase + 2][8*colh];
      a = __builtin_amdgcn_mfma_f32_16x16x32_bf16(af1, bfr1, a, 0,0,0);
      bf16x8 af2 = *(const bf16x8*)&candT[rbase + 4][8*colh];
      a = __builtin_amdgcn_mfma_f32_16x16x32_bf16(af2, bfr2, a, 0,0,0);
      #pragma unroll
      for (int off=1; off<16; off<<=1){
        #pragma unroll
        for (int r=0;r<4;r++){
          float o = __shfl_xor(a[r], off, 64);
          a[r] = fmaxf(a[r], o);
        }
      }
      if (lm == 0){
        float4 st; st.x=a[0]; st.y=a[1]; st.z=a[2]; st.w=a[3];
        *(float4*)&nm_sh[m0 + g*4] = st;
      }
    }
  }
  __syncthreads();   // B3

  // ---- phase D ----
  if (tid<16){
    float e = hx_sh + hc_sh[tid];
    e = (e>=0.f) ? e : 0.2f*e;
    outB[n*16+tid] = e;
    float m = e;
    #pragma unroll
    for (int off=8; off; off>>=1) m = fmaxf(m, __shfl_xor(m, off, 16));
    float ex = __expf(e - m);
    float ssum = ex;
    #pragma unroll
    for (int off=8; off; off>>=1) ssum += __shfl_xor(ssum, off, 16);
    outA[n*16+tid] = ex/ssum;
  }
  float nm = nm_sh[tid];
  if (tid >= 254){
    float a2[16];
    #pragma unroll
    for (int j=0;j<16;j++) a2[j] = kb[j];
    #pragma unroll
    for (int t=0;t<5;++t){
      int pos = tid + t - 2;
      float v = (pos < 256) ? x_sh[pos] : 0.f;
      const float* wb_ = wsum + t*16;
      #pragma unroll
      for (int j=0;j<16;j++) a2[j] = fmaf(v, wb_[j], a2[j]);
    }
    if (tid == 254){
      #pragma unroll
      for (int j=0;j<16;j++) a2[j] += corr_sh[0][j];
    } else {
      #pragma unroll
      for (int j=0;j<16;j++) a2[j] += corr_sh[1][j] + corr_sh[2][j];
    }
    im1 = a2[0];
    #pragma unroll
    for (int j=1;j<16;j++) im1 = fmaxf(im1, a2[j]);
  }
  float im2 = nm;
  if (tid < 2){
    float a3[16];
    if (tid == 0){
      #pragma unroll
      for (int j=0;j<16;j++)
        a3[j] = kb[j] + wsum[0*16+j]*x_sh[254] + wsum[1*16+j]*x_sh[255]
              + corr_sh[3][j] + corr_sh[4][j] + corr_sh[5][j];
    } else {
      #pragma unroll
      for (int j=0;j<16;j++)
        a3[j] = kb[j] + wsum[0*16+j]*x_sh[255]
              + corr_sh[6][j] + corr_sh[7][j] + corr_sh[8][j] + corr_sh[9][j];
    }
    im2 = a3[0];
    #pragma unroll
    for (int j=1;j<16;j++) im2 = fmaxf(im2, a3[j]);
  }

  inbf[1 + tid]   = f2bf(x1v);
  inbf[257 + tid] = f2bf(im1);
  inbf[513 + tid] = f2bf(im2);
  inbf[769 + tid] = f2bf(nm);
  if (tid == 0){ inbf[0] = f2bf(pred_sh); ws[WS_PRED + n] = pred_sh; }
  if (tid < 63) inbf[1025 + tid] = 0;
}

// ---------------- K2b: bf16 MFMA GEMM [8192x1088]x[1088x256] + epilogue ----------------
// One block = 32 rows x ALL 256 cols (the w3-dot needs the full row before relu).
__global__ __launch_bounds__(256) void k2b_mlp(
    const float* __restrict__ ws, const float* __restrict__ w3, const float* __restrict__ b3,
    float* __restrict__ out0){
  __shared__ __align__(16) u16 A_sh[32][72];
  __shared__ __align__(16) u16 B_sh[256][72];
  __shared__ float pr[32][2];
  int tid = threadIdx.x;
  int r0 = blockIdx.x * 32;
  const u16* inbf = (const u16*)(ws + WS_INBF);
  const u16* w12t = (const u16*)(ws + WS_W12T);
  int lane = tid & 63, wv = tid >> 6;
  int lm = lane & 15, g = lane >> 4;
  int mt = wv & 1, nh = wv >> 1;       // wave: rows mt*16.., cols nh*128..
  f32x4 acc[8];
  #pragma unroll
  for (int q=0;q<8;q++){
    float b = ws[WS_B12 + (nh*8+q)*16 + lm];
    acc[q][0]=b; acc[q][1]=b; acc[q][2]=b; acc[q][3]=b;
  }
  int arow = tid >> 3, ak0 = (tid & 7)*8;
  const u16* asrc_p = inbf + (size_t)(r0+arow)*KPAD + ak0;
  const u16* bsrc_p = w12t + (size_t)tid*KPAD;
  for (int kt=0; kt<17; ++kt){
    __syncthreads();   // WAR: previous iter's reads done before overwrite
    *(bf16x8*)&A_sh[arow][ak0] = *(const bf16x8*)(asrc_p + kt*64);
    #pragma unroll
    for (int j=0;j<8;j++)
      *(bf16x8*)&B_sh[tid][8*j] = *(const bf16x8*)(bsrc_p + kt*64 + 8*j);
    __syncthreads();
    #pragma unroll
    for (int ks=0; ks<2; ++ks){
      bf16x8 af = *(const bf16x8*)&A_sh[mt*16+lm][ks*32 + g*8];
      #pragma unroll
      for (int q=0;q<8;q++){
        bf16x8 bf_ = *(const bf16x8*)&B_sh[(nh*8+q)*16+lm][ks*32 + g*8];
        acc[q] = __builtin_amdgcn_mfma_f32_16x16x32_bf16(af, bf_, acc[q], 0,0,0);
      }
    }
  }
  float w3v[8];
  #pragma unroll
  for (int q=0;q<8;q++) w3v[q] = w3[(nh*8+q)*16 + lm];
  #pragma unroll
  for (int j=0;j<4;j++){
    float p = 0.f;
    #pragma unroll
    for (int q=0;q<8;q++) p += fmaxf(acc[q][j], 0.f) * w3v[q];
    #pragma unroll
    for (int off=1; off<16; off<<=1) p += __shfl_xor(p, off, 64);
    if (lm == 0) pr[mt*16 + g*4 + j][nh] = p;
  }
  __syncthreads();
  if (tid < 32){
    float s = pr[tid][0] + pr[tid][1] + b3[0];
    out0[r0 + tid] = ws[WS_PRED + r0 + tid] + fmaxf(s, 0.f);
  }
}

// ---------------- Fallback: fused path (ws too small) ----------------
__global__ __launch_bounds__(256) void k2_fused(
    const float* __restrict__ X, const float* __restrict__ Xtr, const float* __restrict__ ytr,
    const float* __restrict__ ndist, const float* __restrict__ mtr, const float* __restrict__ mb,
    const int* __restrict__ nind,
    const float* __restrict__ ws,
    const float* __restrict__ w3, const float* __restrict__ b3,
    float* __restrict__ out0, float* __restrict__ outA, float* __restrict__ outB){
  __shared__ float x_sh[256];
  __shared__ float cand_sh[16][256];
  __shared__ __align__(16) float in_sh[ROWS][1028];
  __shared__ float corr_sh[10][16];
  __shared__ float wgt_sh[16];
  __shared__ int   idx_sh[16];
  __shared__ float red_sh[ROWS][4];
  __shared__ float hx_sh;
  __shared__ float pred_s[ROWS];
  __shared__ float hc_sh[16];

  int n0 = blockIdx.x * ROWS;
  int tid = threadIdx.x;
  const float* vsrc = ws + WS_VSRC;
  const float* vdst = ws + WS_VDST;
  const float* wcv  = ws + WS_WCONV;
  const float* wsum = ws + WS_WSUM;
  const float* kb   = ws + WS_KB;

  for (int r = 0; r < ROWS; ++r){
    int n = n0 + r;
    __syncthreads();
    float xv = X[n*256+tid];
    x_sh[tid] = xv;
    float xm = xv * mb[n*256+tid];
    float part = xm * vsrc[tid];
    #pragma unroll
    for (int off=32; off; off>>=1) part += __shfl_xor(part, off, 64);
    if ((tid&63)==0) red_sh[0][tid>>6] = part;
    __syncthreads();
    if (tid==0) hx_sh = red_sh[0][0]+red_sh[0][1]+red_sh[0][2]+red_sh[0][3];
    if (tid<16){
      int j = nind[n*16+tid];
      idx_sh[tid] = j;
      float d = ndist[n*16+tid];
      float inv = 1.f/(d + 1e-8f);
      float s = inv;
      #pragma unroll
      for (int off=8; off; off>>=1) s += __shfl_xor(s, off, 16);
      float w = inv/s;
      wgt_sh[tid] = w;
      float pp = ytr[j] * w;
      #pragma unroll
      for (int off=8; off; off>>=1) pp += __shfl_xor(pp, off, 16);
      if (tid==0){ pred_s[r] = pp; in_sh[r][0] = pp; }
    }
    __syncthreads();
    {
      int kk4 = tid >> 6;
      int c4 = (tid & 63) * 4;
      #pragma unroll
      for (int g=0; g<4; ++g){
        int k = g*4 + kk4;
        size_t basei = (size_t)idx_sh[k]*256 + c4;
        float4 xv4 = *(const float4*)(Xtr + basei);
        float4 mv4 = *(const float4*)(mtr + basei);
        float4 cv;
        cv.x = xv4.x*mv4.x; cv.y = xv4.y*mv4.y; cv.z = xv4.z*mv4.z; cv.w = xv4.w*mv4.w;
        *(float4*)&cand_sh[k][c4] = cv;
      }
    }
    __syncthreads();
    {
      int k = tid>>4, d0 = tid&15;
      float s = 0.f;
      #pragma unroll
      for (int i=0;i<16;i++){ int d = d0 + i*16; s += cand_sh[k][d]*vdst[d]; }
      #pragma unroll
      for (int off=8; off; off>>=1) s += __shfl_xor(s, off, 16);
      if (d0==0) hc_sh[k] = s;
    }
    __syncthreads();
    if (tid<16){
      float e = hx_sh + hc_sh[tid];
      e = (e>=0.f) ? e : 0.2f*e;
      outB[n*16+tid] = e;
      float m = e;
      #pragma unroll
      for (int off=8; off; off>>=1) m = fmaxf(m, __shfl_xor(m, off, 16));
      float ex = __expf(e - m);
      float ssum = ex;
      #pragma unroll
      for (int off=8; off; off>>=1) ssum += __shfl_xor(ssum, off, 16);
      outA[n*16+tid] = ex/ssum;
    }
    #pragma unroll
    for (int k=0;k<16;k++) cand_sh[k][tid] *= wgt_sh[k];
    __syncthreads();
    if (tid < 160){
      const int tt[10] = {4,3,4,2,3,4,1,2,3,4};
      const int pp[10] = {0,0,1,0,1,2,0,1,2,3};
      int pair = tid >> 4, co = tid & 15;
      int t = tt[pair], p = pp[pair];
      float s = 0.f;
      #pragma unroll
      for (int ci=0; ci<16; ++ci) s += wcv[(ci*5+t)*16+co] * cand_sh[ci][p];
      corr_sh[pair][co] = s;
    }
    float acc[16];
    #pragma unroll
    for (int j=0;j<16;j++) acc[j] = kb[j];
    for (int ci=0; ci<16; ++ci){
      const float* wci = wcv + ci*80;
      #pragma unroll
      for (int t=0;t<5;++t){
        int pos = tid + t - 2;
        float v = cand_sh[ci][pos & 255];
        v = (pos >= 0 && pos < 256) ? v : 0.f;
        const float* wb_ = wci + t*16;
        #pragma unroll
        for (int j=0;j<16;j++) acc[j] = fmaf(v, wb_[j], acc[j]);
      }
    }
    float nm = acc[0];
    #pragma unroll
    for (int j=1;j<16;j++) nm = fmaxf(nm, acc[j]);
    float a2[16];
    #pragma unroll
    for (int j=0;j<16;j++) a2[j] = kb[j];
    #pragma unroll
    for (int t=0;t<5;++t){
      int pos = tid + t - 2;
      float v = x_sh[pos & 255];
      v = (pos >= 0 && pos < 256) ? v : 0.f;
      const float* wb_ = wsum + t*16;
      #pragma unroll
      for (int j=0;j<16;j++) a2[j] = fmaf(v, wb_[j], a2[j]);
    }
    __syncthreads();
    if (tid == 254){
      #pragma unroll
      for (int j=0;j<16;j++) a2[j] += corr_sh[0][j];
    }
    if (tid == 255){
      #pragma unroll
      for (int j=0;j<16;j++) a2[j] += corr_sh[1][j] + corr_sh[2][j];
    }
    float im1 = a2[0];
    #pragma unroll
    for (int j=1;j<16;j++) im1 = fmaxf(im1, a2[j]);
    float im2 = nm;
    if (tid < 2){
      float a3[16];
      if (tid == 0){
        #pragma unroll
        for (int j=0;j<16;j++)
          a3[j] = kb[j] + wsum[0*16+j]*x_sh[254] + wsum[1*16+j]*x_sh[255]
                + corr_sh[3][j] + corr_sh[4][j] + corr_sh[5][j];
      } else {
        #pragma unroll
        for (int j=0;j<16;j++)
          a3[j] = kb[j] + wsum[0*16+j]*x_sh[255]
                + corr_sh[6][j] + corr_sh[7][j] + corr_sh[8][j] + corr_sh[9][j];
      }
      im2 = a3[0];
      #pragma unroll
      for (int j=1;j<16;j++) im2 = fmaxf(im2, a3[j]);
    }
    float x1v = ws[WS_C1B];
    #pragma unroll
    for (int t=0;t<3;++t){
      int pos = tid + t - 1;
      float v = x_sh[pos & 255];
      v = (pos>=0 && pos<256) ? v : 0.f;
      x1v = fmaf(v, ws[WS_C1W+t], x1v);
    }
    in_sh[r][1 + tid]   = x1v;
    in_sh[r][257 + tid] = im1;
    in_sh[r][513 + tid] = im2;
    in_sh[r][769 + tid] = nm;
  }
  __syncthreads();
  const float* W12 = ws + WS_W12;
  float b12v = ws[WS_B12 + tid];
  float z[ROWS];
  #pragma unroll
  for (int r=0;r<ROWS;r++) z[r] = b12v;
  for (int c=0; c<1024; c+=4){
    float w0 = W12[(size_t)(c+0)*256 + tid];
    float w1v = W12[(size_t)(c+1)*256 + tid];
    float w2v = W12[(size_t)(c+2)*256 + tid];
    float w3v_ = W12[(size_t)(c+3)*256 + tid];
    #pragma unroll
    for (int r=0;r<ROWS;r++){
      float4 iv = *(const float4*)&in_sh[r][c];
      z[r] = fmaf(iv.x, w0, z[r]);
      z[r] = fmaf(iv.y, w1v, z[r]);
      z[r] = fmaf(iv.z, w2v, z[r]);
      z[r] = fmaf(iv.w, w3v_, z[r]);
    }
  }
  {
    float wl = W12[(size_t)1024*256 + tid];
    #pragma unroll
    for (int r=0;r<ROWS;r++) z[r] = fmaf(in_sh[r][1024], wl, z[r]);
  }
  float w3v = w3[tid];
  #pragma unroll
  for (int r=0;r<ROWS;r++){
    float p = fmaxf(z[r], 0.f) * w3v;
    #pragma unroll
    for (int off=32; off; off>>=1) p += __shfl_xor(p, off, 64);
    if ((tid&63)==0) red_sh[r][tid>>6] = p;
  }
  __syncthreads();
  if (tid < ROWS){
    float s = red_sh[tid][0]+red_sh[tid][1]+red_sh[tid][2]+red_sh[tid][3] + b3[0];
    float x3 = fmaxf(s, 0.f);
    out0[n0 + tid] = pred_s[tid] + x3;
  }
}

extern "C" void kernel_launch(void* const* d_in, const int* in_sizes, int n_in,
                              void* d_out, int out_size, void* d_ws, size_t ws_size,
                              hipStream_t stream){
  const float* X    = (const float*)d_in[0];
  const float* Xtr  = (const float*)d_in[1];
  const float* ytr  = (const float*)d_in[2];
  const float* nd   = (const float*)d_in[3];
  const float* mtr  = (const float*)d_in[4];
  const float* mb   = (const float*)d_in[5];
  const float* Watt = (const float*)d_in[6];
  const float* asrc = (const float*)d_in[7];
  const float* adst = (const float*)d_in[8];
  const float* w1   = (const float*)d_in[9];
  const float* b1   = (const float*)d_in[10];
  const float* w2   = (const float*)d_in[11];
  const float* b2   = (const float*)d_in[12];
  const float* w3   = (const float*)d_in[13];
  const float* b3   = (const float*)d_in[14];
  const float* c1w  = (const float*)d_in[15];
  const float* c1b  = (const float*)d_in[16];
  const float* ckw  = (const float*)d_in[17];
  const float* ckb  = (const float*)d_in[18];
  const int* nind = (const int*)d_in[19];
  float* ws = (float*)d_ws;
  float* out0 = (float*)d_out;
  float* outA = out0 + NO;
  float* outB = out0 + NO + NO*KNN;

  k0_prep<<<dim3(4), dim3(256), 0, stream>>>(Watt, asrc, adst, b1, w2, b2, c1w, c1b, ckw, ckb, ws);
  k1_fold<<<dim3(68), dim3(256), 0, stream>>>(w1, w2, ws);
  if (ws_size >= WS_NEED_BYTES){
    k2a_stage<<<dim3(NO), dim3(256), 0, stream>>>(X, Xtr, ytr, nd, mtr, mb, nind,
                                                  ws, outA, outB);
    k2b_mlp<<<dim3(NO/32), dim3(256), 0, stream>>>((const float*)ws, w3, b3, out0);
  } else {
    k2_fused<<<dim3(NO/ROWS), dim3(256), 0, stream>>>(X, Xtr, ytr, nd, mtr, mb, nind,
                                                      (const float*)ws, w3, b3,
                                                      out0, outA, outB);
  }
}

// Round 11
// 138.073 us; speedup vs baseline: 2.6381x; 1.1246x over previous
//
#include <hip/hip_runtime.h>

#define NO 8192
#define NTRAIN 100000
#define DIM 256
#define KNN 16
#define ROWS 8
#define KPAD 1088

// ws layout (float offsets)
#define WS_VSRC 0
#define WS_VDST 256
#define WS_B12  512
#define WS_WCONV 768        // [ci][t][co] f32, 1280
#define WS_WSUM 2048        // [t][co] f32, 80
#define WS_KB   2128        // 16
#define WS_C1W  2144        // 3
#define WS_C1B  2147        // 1
#define WS_WB   2176        // conv MFMA W-frags [3][64][8] u16
#define WS_W12  4096        // f32 [1040][256] (fallback path)
#define WS_W12T 270336      // u16 [256][1088]
#define WS_PRED 409600      // f32 [8192]
#define WS_INBF 417792      // u16 [8192][1088]
#define WS_END  (417792 + 4456448)
#define WS_NEED_BYTES ((size_t)WS_END * 4)

typedef unsigned int u32;
typedef unsigned short u16;
typedef __attribute__((ext_vector_type(8))) short bf16x8;
typedef __attribute__((ext_vector_type(4))) float f32x4;

__device__ __forceinline__ u16 f2bf(float f){
  u32 u = __float_as_uint(f);
  u32 r = (u + 0x7FFFu + ((u>>16)&1u)) >> 16;
  return (u16)r;
}
__device__ __forceinline__ float bf2f(u16 v){ return __uint_as_float(((u32)v)<<16); }

// ---------------- K1: fold W12 + (merged) k0 precomputes ----------------
__global__ __launch_bounds__(256) void k1_fold(
    const float* __restrict__ w1, const float* __restrict__ w2,
    const float* __restrict__ Watt, const float* __restrict__ asrc, const float* __restrict__ adst,
    const float* __restrict__ b1, const float* __restrict__ b2,
    const float* __restrict__ c1w, const float* __restrict__ c1b,
    const float* __restrict__ ckw, const float* __restrict__ ckb,
    float* __restrict__ ws){
  int tid = threadIdx.x;
  if (blockIdx.x >= 68){
    int b = blockIdx.x - 68;
    if (b < 2){
      __shared__ float a_sh[256];
      const float* av = (b==0) ? asrc : adst;
      a_sh[tid] = av[tid];
      __syncthreads();
      const float4* wp = (const float4*)(Watt + tid*DIM);
      float s = 0.f;
      for (int i=0;i<DIM/4;i++){
        float4 u = wp[i];
        int o = i*4;
        s += u.x*a_sh[o+0] + u.y*a_sh[o+1] + u.z*a_sh[o+2] + u.w*a_sh[o+3];
      }
      ws[(b==0?WS_VSRC:WS_VDST) + tid] = s;
    } else if (b == 2){
      float s = b2[tid];
      for (int h=0; h<512; ++h) s += b1[h] * w2[h*256+tid];
      ws[WS_B12+tid] = s;
    } else {
      for (int idx=tid; idx<1280; idx+=256){
        int co = idx/80, r = idx%80; int ci = r/5, t = r%5;
        ws[WS_WCONV + (ci*5+t)*16 + co] = ckw[idx];
      }
      // conv MFMA weight frags: (g,j)->k convention: ci=8*(g&1)+j, t=2*s+(g>>1)
      {
        u16* wb = (u16*)(ws + WS_WB);
        for (int e = tid; e < 1536; e += 256){
          int s = e >> 9, rem = e & 511, lane = rem >> 3, j = rem & 7;
          int g = lane >> 4, nn = lane & 15;
          int ci = 8*(g&1) + j, t = 2*s + (g>>1);
          float v = (t < 5) ? ckw[nn*80 + ci*5 + t] : 0.f;
          wb[e] = f2bf(v);
        }
      }
      __syncthreads();
      if (tid < 80){
        int t = tid/16, co = tid%16;
        float s = 0.f;
        for (int ci=0;ci<16;ci++) s += ws[WS_WCONV + (ci*5+t)*16 + co];
        ws[WS_WSUM + t*16 + co] = s;
      }
      if (tid < 16) ws[WS_KB + tid] = ckb[tid];
      if (tid < 3)  ws[WS_C1W + tid] = c1w[tid];
      if (tid == 3) ws[WS_C1B] = c1b[0];
    }
    return;
  }
  // ---- W12 fold ----
  __shared__ float aT[16][20];
  __shared__ float t16[16][257];
  float* w12 = ws + WS_W12;
  u16* w12t = (u16*)(ws + WS_W12T);
  int r0 = blockIdx.x * 16;
  float acc[16];
  #pragma unroll
  for (int j=0;j<16;j++) acc[j] = 0.f;
  int kk = tid & 15, rr = tid >> 4;
  for (int kt=0; kt<32; ++kt){
    int row = r0 + rr;
    float av = (row < 1025) ? w1[row*512 + kt*16 + kk] : 0.f;
    __syncthreads();
    aT[kk][rr] = av;
    __syncthreads();
    #pragma unroll
    for (int k=0;k<16;++k){
      float bv = w2[(kt*16+k)*256 + tid];
      const float* a = aT[k];
      #pragma unroll
      for (int j=0;j<16;j++) acc[j] = fmaf(a[j], bv, acc[j]);
    }
  }
  #pragma unroll
  for (int j=0;j<16;j++){
    int row = r0 + j;
    // GUARD: w12 f32 buffer is 1040 rows; rows 1040..1087 would smash W12T
    if (row < 1040) w12[(size_t)row*256 + tid] = (row < 1025) ? acc[j] : 0.f;
    t16[j][tid] = (row < 1025) ? acc[j] : 0.f;
  }
  __syncthreads();
  for (int p=0; p<16; ++p){
    int nn = p*16 + (tid>>4);
    int kl = tid & 15;
    w12t[(size_t)nn*KPAD + r0 + kl] = f2bf(t16[kl][nn]);
  }
}

// ---------------- K2a: stage-1, one row per block, 2 barriers, early gather ----------------
__global__ __launch_bounds__(256) void k2a_stage(
    const float* __restrict__ X, const float* __restrict__ Xtr, const float* __restrict__ ytr,
    const float* __restrict__ ndist, const float* __restrict__ mtr, const float* __restrict__ mb,
    const int* __restrict__ nind,
    float* __restrict__ ws,
    float* __restrict__ outA, float* __restrict__ outB){
  __shared__ float x_sh[256];
  __shared__ __align__(16) short candT[262][24];   // [pos+2][ci] bf16 weighted
  __shared__ float nm_sh[256];
  __shared__ float corr_sh[10][16];
  __shared__ float red_sh[4];
  __shared__ float hc_sh[16];
  __shared__ float pred_sh;

  int n = blockIdx.x;
  int tid = threadIdx.x;
  const float* vsrc = ws + WS_VSRC;
  const float* vdst = ws + WS_VDST;
  const float* wcv  = ws + WS_WCONV;
  const float* wsum = ws + WS_WSUM;
  const float* kb   = ws + WS_KB;
  u16* inbf = (u16*)(ws + WS_INBF) + (size_t)n*KPAD;

  // ---- phase A: in-wave idx/weights, gather issues immediately ----
  int l16 = tid & 15;
  int j16 = nind[n*16 + l16];
  float d16 = ndist[n*16 + l16];
  float inv = 1.f/(d16 + 1e-8f);
  float ssum = inv;
  #pragma unroll
  for (int off=8; off; off>>=1) ssum += __shfl_xor(ssum, off, 16);
  float w16 = inv / ssum;

  {
    u32* dst = (u32*)&candT[2+tid][0];
    #pragma unroll
    for (int q=0;q<8;q++){
      int ja = __shfl(j16, 2*q, 16), jb = __shfl(j16, 2*q+1, 16);
      float wa = __shfl(w16, 2*q, 16), wb2 = __shfl(w16, 2*q+1, 16);
      int ia = ja*256 + tid, ib = jb*256 + tid;
      float va = Xtr[ia]*mtr[ia]*wa;
      float vb = Xtr[ib]*mtr[ib]*wb2;
      dst[q] = (u32)f2bf(va) | ((u32)f2bf(vb) << 16);
    }
  }
  if (tid < 6){
    int r = (tid < 2) ? tid : 256 + tid;  // zero rows 0,1,258..261
    u32* dst = (u32*)&candT[r][0];
    #pragma unroll
    for (int q=0;q<12;q++) dst[q] = 0;
  }
  float xv = X[n*256+tid];
  x_sh[tid] = xv;
  float part = xv * mb[n*256+tid] * vsrc[tid];
  #pragma unroll
  for (int off=32; off; off>>=1) part += __shfl_xor(part, off, 64);
  if ((tid&63)==0) red_sh[tid>>6] = part;
  if (tid < 16){
    float pp = ytr[j16] * w16;
    #pragma unroll
    for (int off=8; off; off>>=1) pp += __shfl_xor(pp, off, 16);
    if (tid==0) pred_sh = pp;
  }
  __syncthreads();   // B1

  // ---- phase C ----
  // h_c from weighted bf16, divided by weight
  {
    int k = tid>>4, d0 = tid&15;
    float s = 0.f;
    #pragma unroll
    for (int i=0;i<16;i++){
      int d = d0 + i*16;
      s += bf2f((u16)candT[2+d][k]) * vdst[d];
    }
    #pragma unroll
    for (int off=8; off; off>>=1) s += __shfl_xor(s, off, 16);
    float wk = __shfl(w16, k, 16);
    if (d0==0) hc_sh[k] = s / wk;
  }
  // correction terms from candT
  if (tid < 160){
    const int tt[10] = {4,3,4,2,3,4,1,2,3,4};
    const int pp[10] = {0,0,1,0,1,2,0,1,2,3};
    int pair = tid >> 4, co = tid & 15;
    int t = tt[pair], p = pp[pair];
    float s = 0.f;
    #pragma unroll
    for (int ci=0; ci<16; ++ci)
      s += wcv[(ci*5+t)*16+co] * bf2f((u16)candT[2+p][ci]);
    corr_sh[pair][co] = s;
  }
  // im1 (wsum conv); tid>=254 corrected in phase D
  float im1;
  {
    float a2[16];
    #pragma unroll
    for (int j=0;j<16;j++) a2[j] = kb[j];
    #pragma unroll
    for (int t=0;t<5;++t){
      int pos = tid + t - 2;
      float v = x_sh[pos & 255];
      v = (pos >= 0 && pos < 256) ? v : 0.f;
      const float* wb_ = wsum + t*16;
      #pragma unroll
      for (int j=0;j<16;j++) a2[j] = fmaf(v, wb_[j], a2[j]);
    }
    im1 = a2[0];
    #pragma unroll
    for (int j=1;j<16;j++) im1 = fmaxf(im1, a2[j]);
  }
  // X1
  float x1v = ws[WS_C1B];
  #pragma unroll
  for (int t=0;t<3;++t){
    int pos = tid + t - 1;
    float v = x_sh[pos & 255];
    v = (pos>=0 && pos<256) ? v : 0.f;
    x1v = fmaf(v, ws[WS_C1W+t], x1v);
  }
  // Neighbors conv via MFMA, swapped operands: C[co][l] -> cheap co-max
  {
    int lane = tid & 63, wave = tid >> 6;
    int g    = lane >> 4;
    int lm   = lane & 15;
    int colh = g & 1;
    int tg   = g >> 1;
    const u16* wb = (const u16*)(ws + WS_WB);
    bf16x8 wfr0 = *(const bf16x8*)(wb + 0*512 + lane*8);
    bf16x8 wfr1 = *(const bf16x8*)(wb + 1*512 + lane*8);
    bf16x8 wfr2 = *(const bf16x8*)(wb + 2*512 + lane*8);
    float4 kb4 = *(const float4*)&kb[g*4];
    #pragma unroll
    for (int i=0;i<4;i++){
      int m0 = (wave*4 + i) * 16;
      f32x4 a = {kb4.x, kb4.y, kb4.z, kb4.w};
      int rbase = m0 + lm + tg;
      bf16x8 cf0 = *(const bf16x8*)&candT[rbase + 0][8*colh];
      a = __builtin_amdgcn_mfma_f32_16x16x32_bf16(wfr0, cf0, a, 0,0,0);
      bf16x8 cf1 = *(const bf16x8*)&candT[rbase + 2][8*colh];
      a = __builtin_amdgcn_mfma_f32_16x16x32_bf16(wfr1, cf1, a, 0,0,0);
      bf16x8 cf2 = *(const bf16x8*)&candT[rbase + 4][8*colh];
      a = __builtin_amdgcn_mfma_f32_16x16x32_bf16(wfr2, cf2, a, 0,0,0);
      float mx = fmaxf(fmaxf(a[0], a[1]), fmaxf(a[2], a[3]));
      mx = fmaxf(mx, __shfl_xor(mx, 16, 64));
      mx = fmaxf(mx, __shfl_xor(mx, 32, 64));
      if (g == 0) nm_sh[m0 + lm] = mx;
    }
  }
  __syncthreads();   // B2

  // ---- phase D ----
  if (tid<16){
    float hx = red_sh[0]+red_sh[1]+red_sh[2]+red_sh[3];
    float e = hx + hc_sh[tid];
    e = (e>=0.f) ? e : 0.2f*e;
    outB[n*16+tid] = e;
    float m = e;
    #pragma unroll
    for (int off=8; off; off>>=1) m = fmaxf(m, __shfl_xor(m, off, 16));
    float ex = __expf(e - m);
    float s2 = ex;
    #pragma unroll
    for (int off=8; off; off>>=1) s2 += __shfl_xor(s2, off, 16);
    outA[n*16+tid] = ex/s2;
  }
  float nm = nm_sh[tid];
  if (tid >= 254){
    float a2[16];
    #pragma unroll
    for (int j=0;j<16;j++) a2[j] = kb[j];
    #pragma unroll
    for (int t=0;t<5;++t){
      int pos = tid + t - 2;
      float v = (pos < 256) ? x_sh[pos] : 0.f;
      const float* wb_ = wsum + t*16;
      #pragma unroll
      for (int j=0;j<16;j++) a2[j] = fmaf(v, wb_[j], a2[j]);
    }
    if (tid == 254){
      #pragma unroll
      for (int j=0;j<16;j++) a2[j] += corr_sh[0][j];
    } else {
      #pragma unroll
      for (int j=0;j<16;j++) a2[j] += corr_sh[1][j] + corr_sh[2][j];
    }
    im1 = a2[0];
    #pragma unroll
    for (int j=1;j<16;j++) im1 = fmaxf(im1, a2[j]);
  }
  float im2 = nm;
  if (tid < 2){
    float a3[16];
    if (tid == 0){
      #pragma unroll
      for (int j=0;j<16;j++)
        a3[j] = kb[j] + wsum[0*16+j]*x_sh[254] + wsum[1*16+j]*x_sh[255]
              + corr_sh[3][j] + corr_sh[4][j] + corr_sh[5][j];
    } else {
      #pragma unroll
      for (int j=0;j<16;j++)
        a3[j] = kb[j] + wsum[0*16+j]*x_sh[255]
              + corr_sh[6][j] + corr_sh[7][j] + corr_sh[8][j] + corr_sh[9][j];
    }
    im2 = a3[0];
    #pragma unroll
    for (int j=1;j<16;j++) im2 = fmaxf(im2, a3[j]);
  }

  inbf[1 + tid]   = f2bf(x1v);
  inbf[257 + tid] = f2bf(im1);
  inbf[513 + tid] = f2bf(im2);
  inbf[769 + tid] = f2bf(nm);
  if (tid == 0){ inbf[0] = f2bf(pred_sh); ws[WS_PRED + n] = pred_sh; }
  if (tid < 63) inbf[1025 + tid] = 0;
}

// ---------------- K2b: bf16 MFMA GEMM, pipelined loads ----------------
__global__ __launch_bounds__(256) void k2b_mlp(
    const float* __restrict__ ws, const float* __restrict__ w3, const float* __restrict__ b3,
    float* __restrict__ out0){
  __shared__ __align__(16) u16 A_sh[32][72];
  __shared__ __align__(16) u16 B_sh[256][72];
  __shared__ float pr[32][2];
  int tid = threadIdx.x;
  int r0 = blockIdx.x * 32;
  const u16* inbf = (const u16*)(ws + WS_INBF);
  const u16* w12t = (const u16*)(ws + WS_W12T);
  int lane = tid & 63, wv = tid >> 6;
  int lm = lane & 15, g = lane >> 4;
  int mt = wv & 1, nh = wv >> 1;
  f32x4 acc[8];
  #pragma unroll
  for (int q=0;q<8;q++){
    float b = ws[WS_B12 + (nh*8+q)*16 + lm];
    acc[q][0]=b; acc[q][1]=b; acc[q][2]=b; acc[q][3]=b;
  }
  int arow = tid >> 3, ak0 = (tid & 7)*8;
  const u16* ap = inbf + (size_t)(r0+arow)*KPAD + ak0;
  const u16* bp = w12t + (size_t)tid*KPAD;
  bf16x8 aR = *(const bf16x8*)ap;
  bf16x8 bR[8];
  #pragma unroll
  for (int j=0;j<8;j++) bR[j] = *(const bf16x8*)(bp + 8*j);
  for (int kt=0; kt<17; ++kt){
    if (kt) __syncthreads();      // WAR vs previous iter's LDS reads
    *(bf16x8*)&A_sh[arow][ak0] = aR;
    #pragma unroll
    for (int j=0;j<8;j++) *(bf16x8*)&B_sh[tid][8*j] = bR[j];
    __syncthreads();
    if (kt < 16){
      aR = *(const bf16x8*)(ap + (kt+1)*64);
      #pragma unroll
      for (int j=0;j<8;j++) bR[j] = *(const bf16x8*)(bp + (kt+1)*64 + 8*j);
    }
    #pragma unroll
    for (int ks=0; ks<2; ++ks){
      bf16x8 af = *(const bf16x8*)&A_sh[mt*16+lm][ks*32 + g*8];
      #pragma unroll
      for (int q=0;q<8;q++){
        bf16x8 bf_ = *(const bf16x8*)&B_sh[(nh*8+q)*16+lm][ks*32 + g*8];
        acc[q] = __builtin_amdgcn_mfma_f32_16x16x32_bf16(af, bf_, acc[q], 0,0,0);
      }
    }
  }
  float w3v[8];
  #pragma unroll
  for (int q=0;q<8;q++) w3v[q] = w3[(nh*8+q)*16 + lm];
  #pragma unroll
  for (int j=0;j<4;j++){
    float p = 0.f;
    #pragma unroll
    for (int q=0;q<8;q++) p += fmaxf(acc[q][j], 0.f) * w3v[q];
    #pragma unroll
    for (int off=1; off<16; off<<=1) p += __shfl_xor(p, off, 64);
    if (lm == 0) pr[mt*16 + g*4 + j][nh] = p;
  }
  __syncthreads();
  if (tid < 32){
    float s = pr[tid][0] + pr[tid][1] + b3[0];
    out0[r0 + tid] = ws[WS_PRED + r0 + tid] + fmaxf(s, 0.f);
  }
}

// ---------------- Fallback: fused path (ws too small) ----------------
__global__ __launch_bounds__(256) void k2_fused(
    const float* __restrict__ X, const float* __restrict__ Xtr, const float* __restrict__ ytr,
    const float* __restrict__ ndist, const float* __restrict__ mtr, const float* __restrict__ mb,
    const int* __restrict__ nind,
    const float* __restrict__ ws,
    const float* __restrict__ w3, const float* __restrict__ b3,
    float* __restrict__ out0, float* __restrict__ outA, float* __restrict__ outB){
  __shared__ float x_sh[256];
  __shared__ float cand_sh[16][256];
  __shared__ __align__(16) float in_sh[ROWS][1028];
  __shared__ float corr_sh[10][16];
  __shared__ float wgt_sh[16];
  __shared__ int   idx_sh[16];
  __shared__ float red_sh[ROWS][4];
  __shared__ float hx_sh;
  __shared__ float pred_s[ROWS];
  __shared__ float hc_sh[16];

  int n0 = blockIdx.x * ROWS;
  int tid = threadIdx.x;
  const float* vsrc = ws + WS_VSRC;
  const float* vdst = ws + WS_VDST;
  const float* wcv  = ws + WS_WCONV;
  const float* wsum = ws + WS_WSUM;
  const float* kb   = ws + WS_KB;

  for (int r = 0; r < ROWS; ++r){
    int n = n0 + r;
    __syncthreads();
    float xv = X[n*256+tid];
    x_sh[tid] = xv;
    float xm = xv * mb[n*256+tid];
    float part = xm * vsrc[tid];
    #pragma unroll
    for (int off=32; off; off>>=1) part += __shfl_xor(part, off, 64);
    if ((tid&63)==0) red_sh[0][tid>>6] = part;
    __syncthreads();
    if (tid==0) hx_sh = red_sh[0][0]+red_sh[0][1]+red_sh[0][2]+red_sh[0][3];
    if (tid<16){
      int j = nind[n*16+tid];
      idx_sh[tid] = j;
      float d = ndist[n*16+tid];
      float inv = 1.f/(d + 1e-8f);
      float s = inv;
      #pragma unroll
      for (int off=8; off; off>>=1) s += __shfl_xor(s, off, 16);
      float w = inv/s;
      wgt_sh[tid] = w;
      float pp = ytr[j] * w;
      #pragma unroll
      for (int off=8; off; off>>=1) pp += __shfl_xor(pp, off, 16);
      if (tid==0){ pred_s[r] = pp; in_sh[r][0] = pp; }
    }
    __syncthreads();
    {
      int kk4 = tid >> 6;
      int c4 = (tid & 63) * 4;
      #pragma unroll
      for (int g=0; g<4; ++g){
        int k = g*4 + kk4;
        size_t basei = (size_t)idx_sh[k]*256 + c4;
        float4 xv4 = *(const float4*)(Xtr + basei);
        float4 mv4 = *(const float4*)(mtr + basei);
        float4 cv;
        cv.x = xv4.x*mv4.x; cv.y = xv4.y*mv4.y; cv.z = xv4.z*mv4.z; cv.w = xv4.w*mv4.w;
        *(float4*)&cand_sh[k][c4] = cv;
      }
    }
    __syncthreads();
    {
      int k = tid>>4, d0 = tid&15;
      float s = 0.f;
      #pragma unroll
      for (int i=0;i<16;i++){ int d = d0 + i*16; s += cand_sh[k][d]*vdst[d]; }
      #pragma unroll
      for (int off=8; off; off>>=1) s += __shfl_xor(s, off, 16);
      if (d0==0) hc_sh[k] = s;
    }
    __syncthreads();
    if (tid<16){
      float e = hx_sh + hc_sh[tid];
      e = (e>=0.f) ? e : 0.2f*e;
      outB[n*16+tid] = e;
      float m = e;
      #pragma unroll
      for (int off=8; off; off>>=1) m = fmaxf(m, __shfl_xor(m, off, 16));
      float ex = __expf(e - m);
      float ssum = ex;
      #pragma unroll
      for (int off=8; off; off>>=1) ssum += __shfl_xor(ssum, off, 16);
      outA[n*16+tid] = ex/ssum;
    }
    #pragma unroll
    for (int k=0;k<16;k++) cand_sh[k][tid] *= wgt_sh[k];
    __syncthreads();
    if (tid < 160){
      const int tt[10] = {4,3,4,2,3,4,1,2,3,4};
      const int pp[10] = {0,0,1,0,1,2,0,1,2,3};
      int pair = tid >> 4, co = tid & 15;
      int t = tt[pair], p = pp[pair];
      float s = 0.f;
      #pragma unroll
      for (int ci=0; ci<16; ++ci) s += wcv[(ci*5+t)*16+co] * cand_sh[ci][p];
      corr_sh[pair][co] = s;
    }
    float acc[16];
    #pragma unroll
    for (int j=0;j<16;j++) acc[j] = kb[j];
    for (int ci=0; ci<16; ++ci){
      const float* wci = wcv + ci*80;
      #pragma unroll
      for (int t=0;t<5;++t){
        int pos = tid + t - 2;
        float v = cand_sh[ci][pos & 255];
        v = (pos >= 0 && pos < 256) ? v : 0.f;
        const float* wb_ = wci + t*16;
        #pragma unroll
        for (int j=0;j<16;j++) acc[j] = fmaf(v, wb_[j], acc[j]);
      }
    }
    float nm = acc[0];
    #pragma unroll
    for (int j=1;j<16;j++) nm = fmaxf(nm, acc[j]);
    float a2[16];
    #pragma unroll
    for (int j=0;j<16;j++) a2[j] = kb[j];
    #pragma unroll
    for (int t=0;t<5;++t){
      int pos = tid + t - 2;
      float v = x_sh[pos & 255];
      v = (pos >= 0 && pos < 256) ? v : 0.f;
      const float* wb_ = wsum + t*16;
      #pragma unroll
      for (int j=0;j<16;j++) a2[j] = fmaf(v, wb_[j], a2[j]);
    }
    __syncthreads();
    if (tid == 254){
      #pragma unroll
      for (int j=0;j<16;j++) a2[j] += corr_sh[0][j];
    }
    if (tid == 255){
      #pragma unroll
      for (int j=0;j<16;j++) a2[j] += corr_sh[1][j] + corr_sh[2][j];
    }
    float im1 = a2[0];
    #pragma unroll
    for (int j=1;j<16;j++) im1 = fmaxf(im1, a2[j]);
    float im2 = nm;
    if (tid < 2){
      float a3[16];
      if (tid == 0){
        #pragma unroll
        for (int j=0;j<16;j++)
          a3[j] = kb[j] + wsum[0*16+j]*x_sh[254] + wsum[1*16+j]*x_sh[255]
                + corr_sh[3][j] + corr_sh[4][j] + corr_sh[5][j];
      } else {
        #pragma unroll
        for (int j=0;j<16;j++)
          a3[j] = kb[j] + wsum[0*16+j]*x_sh[255]
                + corr_sh[6][j] + corr_sh[7][j] + corr_sh[8][j] + corr_sh[9][j];
      }
      im2 = a3[0];
      #pragma unroll
      for (int j=1;j<16;j++) im2 = fmaxf(im2, a3[j]);
    }
    float x1v = ws[WS_C1B];
    #pragma unroll
    for (int t=0;t<3;++t){
      int pos = tid + t - 1;
      float v = x_sh[pos & 255];
      v = (pos>=0 && pos<256) ? v : 0.f;
      x1v = fmaf(v, ws[WS_C1W+t], x1v);
    }
    in_sh[r][1 + tid]   = x1v;
    in_sh[r][257 + tid] = im1;
    in_sh[r][513 + tid] = im2;
    in_sh[r][769 + tid] = nm;
  }
  __syncthreads();
  const float* W12 = ws + WS_W12;
  float b12v = ws[WS_B12 + tid];
  float z[ROWS];
  #pragma unroll
  for (int r=0;r<ROWS;r++) z[r] = b12v;
  for (int c=0; c<1024; c+=4){
    float w0 = W12[(size_t)(c+0)*256 + tid];
    float w1v = W12[(size_t)(c+1)*256 + tid];
    float w2v = W12[(size_t)(c+2)*256 + tid];
    float w3v_ = W12[(size_t)(c+3)*256 + tid];
    #pragma unroll
    for (int r=0;r<ROWS;r++){
      float4 iv = *(const float4*)&in_sh[r][c];
      z[r] = fmaf(iv.x, w0, z[r]);
      z[r] = fmaf(iv.y, w1v, z[r]);
      z[r] = fmaf(iv.z, w2v, z[r]);
      z[r] = fmaf(iv.w, w3v_, z[r]);
    }
  }
  {
    float wl = W12[(size_t)1024*256 + tid];
    #pragma unroll
    for (int r=0;r<ROWS;r++) z[r] = fmaf(in_sh[r][1024], wl, z[r]);
  }
  float w3v = w3[tid];
  #pragma unroll
  for (int r=0;r<ROWS;r++){
    float p = fmaxf(z[r], 0.f) * w3v;
    #pragma unroll
    for (int off=32; off; off>>=1) p += __shfl_xor(p, off, 64);
    if ((tid&63)==0) red_sh[r][tid>>6] = p;
  }
  __syncthreads();
  if (tid < ROWS){
    float s = red_sh[tid][0]+red_sh[tid][1]+red_sh[tid][2]+red_sh[tid][3] + b3[0];
    float x3 = fmaxf(s, 0.f);
    out0[n0 + tid] = pred_s[tid] + x3;
  }
}

extern "C" void kernel_launch(void* const* d_in, const int* in_sizes, int n_in,
                              void* d_out, int out_size, void* d_ws, size_t ws_size,
                              hipStream_t stream){
  const float* X    = (const float*)d_in[0];
  const float* Xtr  = (const float*)d_in[1];
  const float* ytr  = (const float*)d_in[2];
  const float* nd   = (const float*)d_in[3];
  const float* mtr  = (const float*)d_in[4];
  const float* mb   = (const float*)d_in[5];
  const float* Watt = (const float*)d_in[6];
  const float* asrc = (const float*)d_in[7];
  const float* adst = (const float*)d_in[8];
  const float* w1   = (const float*)d_in[9];
  const float* b1   = (const float*)d_in[10];
  const float* w2   = (const float*)d_in[11];
  const float* b2   = (const float*)d_in[12];
  const float* w3   = (const float*)d_in[13];
  const float* b3   = (const float*)d_in[14];
  const float* c1w  = (const float*)d_in[15];
  const float* c1b  = (const float*)d_in[16];
  const float* ckw  = (const float*)d_in[17];
  const float* ckb  = (const float*)d_in[18];
  const int* nind = (const int*)d_in[19];
  float* ws = (float*)d_ws;
  float* out0 = (float*)d_out;
  float* outA = out0 + NO;
  float* outB = out0 + NO + NO*KNN;

  k1_fold<<<dim3(72), dim3(256), 0, stream>>>(w1, w2, Watt, asrc, adst, b1, b2,
                                              c1w, c1b, ckw, ckb, ws);
  if (ws_size >= WS_NEED_BYTES){
    k2a_stage<<<dim3(NO), dim3(256), 0, stream>>>(X, Xtr, ytr, nd, mtr, mb, nind,
                                                  ws, outA, outB);
    k2b_mlp<<<dim3(NO/32), dim3(256), 0, stream>>>((const float*)ws, w3, b3, out0);
  } else {
    k2_fused<<<dim3(NO/ROWS), dim3(256), 0, stream>>>(X, Xtr, ytr, nd, mtr, mb, nind,
                                                      (const float*)ws, w3, b3,
                                                      out0, outA, outB);
  }
}

// Round 12
// 134.451 us; speedup vs baseline: 2.7092x; 1.0269x over previous
//
#include <hip/hip_runtime.h>

#define NO 8192
#define NTRAIN 100000
#define DIM 256
#define KNN 16
#define ROWS 8
#define KPAD 1088

// ws layout (float offsets)
#define WS_VSRC 0
#define WS_VDST 256
#define WS_B12  512
#define WS_WCONV 768        // [ci][t][co] f32, 1280
#define WS_WSUM 2048        // [t][co] f32, 80
#define WS_KB   2128        // 16
#define WS_C1W  2144        // 3
#define WS_C1B  2147        // 1
#define WS_WB   2176        // conv MFMA W-frags [3][64][8] u16
#define WS_W12  4096        // f32 [1040][256] (fallback path)
#define WS_W12T 270336      // u16 [256][1088]
#define WS_PRED 409600      // f32 [8192]
#define WS_INBF 417792      // u16 [8192][1088]
#define WS_END  (417792 + 4456448)
#define WS_NEED_BYTES ((size_t)WS_END * 4)

typedef unsigned int u32;
typedef unsigned short u16;
typedef __attribute__((ext_vector_type(8))) short bf16x8;
typedef __attribute__((ext_vector_type(4))) float f32x4;

__device__ __forceinline__ u16 f2bf(float f){
  u32 u = __float_as_uint(f);
  u32 r = (u + 0x7FFFu + ((u>>16)&1u)) >> 16;
  return (u16)r;
}
__device__ __forceinline__ float bf2f(u16 v){ return __uint_as_float(((u32)v)<<16); }

// ---------------- K1: fold W12 + (merged) k0 precomputes ----------------
__global__ __launch_bounds__(256) void k1_fold(
    const float* __restrict__ w1, const float* __restrict__ w2,
    const float* __restrict__ Watt, const float* __restrict__ asrc, const float* __restrict__ adst,
    const float* __restrict__ b1, const float* __restrict__ b2,
    const float* __restrict__ c1w, const float* __restrict__ c1b,
    const float* __restrict__ ckw, const float* __restrict__ ckb,
    float* __restrict__ ws){
  int tid = threadIdx.x;
  if (blockIdx.x >= 68){
    int b = blockIdx.x - 68;
    if (b < 2){
      __shared__ float a_sh[256];
      const float* av = (b==0) ? asrc : adst;
      a_sh[tid] = av[tid];
      __syncthreads();
      const float4* wp = (const float4*)(Watt + tid*DIM);
      float s = 0.f;
      for (int i=0;i<DIM/4;i++){
        float4 u = wp[i];
        int o = i*4;
        s += u.x*a_sh[o+0] + u.y*a_sh[o+1] + u.z*a_sh[o+2] + u.w*a_sh[o+3];
      }
      ws[(b==0?WS_VSRC:WS_VDST) + tid] = s;
    } else if (b == 2){
      float s = b2[tid];
      for (int h=0; h<512; ++h) s += b1[h] * w2[h*256+tid];
      ws[WS_B12+tid] = s;
    } else {
      for (int idx=tid; idx<1280; idx+=256){
        int co = idx/80, r = idx%80; int ci = r/5, t = r%5;
        ws[WS_WCONV + (ci*5+t)*16 + co] = ckw[idx];
      }
      // conv MFMA weight frags: (g,j)->k convention: ci=8*(g&1)+j, t=2*s+(g>>1)
      {
        u16* wb = (u16*)(ws + WS_WB);
        for (int e = tid; e < 1536; e += 256){
          int s = e >> 9, rem = e & 511, lane = rem >> 3, j = rem & 7;
          int g = lane >> 4, nn = lane & 15;
          int ci = 8*(g&1) + j, t = 2*s + (g>>1);
          float v = (t < 5) ? ckw[nn*80 + ci*5 + t] : 0.f;
          wb[e] = f2bf(v);
        }
      }
      __syncthreads();
      if (tid < 80){
        int t = tid/16, co = tid%16;
        float s = 0.f;
        for (int ci=0;ci<16;ci++) s += ws[WS_WCONV + (ci*5+t)*16 + co];
        ws[WS_WSUM + t*16 + co] = s;
      }
      if (tid < 16) ws[WS_KB + tid] = ckb[tid];
      if (tid < 3)  ws[WS_C1W + tid] = c1w[tid];
      if (tid == 3) ws[WS_C1B] = c1b[0];
    }
    return;
  }
  // ---- W12 fold ----
  __shared__ float aT[16][20];
  __shared__ float t16[16][257];
  float* w12 = ws + WS_W12;
  u16* w12t = (u16*)(ws + WS_W12T);
  int r0 = blockIdx.x * 16;
  float acc[16];
  #pragma unroll
  for (int j=0;j<16;j++) acc[j] = 0.f;
  int kk = tid & 15, rr = tid >> 4;
  for (int kt=0; kt<32; ++kt){
    int row = r0 + rr;
    float av = (row < 1025) ? w1[row*512 + kt*16 + kk] : 0.f;
    __syncthreads();
    aT[kk][rr] = av;
    __syncthreads();
    #pragma unroll
    for (int k=0;k<16;++k){
      float bv = w2[(kt*16+k)*256 + tid];
      const float* a = aT[k];
      #pragma unroll
      for (int j=0;j<16;j++) acc[j] = fmaf(a[j], bv, acc[j]);
    }
  }
  #pragma unroll
  for (int j=0;j<16;j++){
    int row = r0 + j;
    // GUARD: w12 f32 buffer is 1040 rows; rows 1040..1087 would smash W12T
    if (row < 1040) w12[(size_t)row*256 + tid] = (row < 1025) ? acc[j] : 0.f;
    t16[j][tid] = (row < 1025) ? acc[j] : 0.f;
  }
  __syncthreads();
  for (int p=0; p<16; ++p){
    int nn = p*16 + (tid>>4);
    int kl = tid & 15;
    w12t[(size_t)nn*KPAD + r0 + kl] = f2bf(t16[kl][nn]);
  }
}

// ---------------- K2a: stage-1, one row per block, batched float4 gather ----------------
__global__ __launch_bounds__(256, 4) void k2a_stage(
    const float* __restrict__ X, const float* __restrict__ Xtr, const float* __restrict__ ytr,
    const float* __restrict__ ndist, const float* __restrict__ mtr, const float* __restrict__ mb,
    const int* __restrict__ nind,
    float* __restrict__ ws,
    float* __restrict__ outA, float* __restrict__ outB){
  __shared__ float x_sh[256];
  __shared__ __align__(16) short candT[262][24];   // [pos+2][ci] bf16 weighted
  __shared__ float nm_sh[256];
  __shared__ float corr_sh[10][16];
  __shared__ float red_sh[4];
  __shared__ float hc_sh[16];
  __shared__ float pred_sh;

  int n = blockIdx.x;
  int tid = threadIdx.x;
  const float* vsrc = ws + WS_VSRC;
  const float* vdst = ws + WS_VDST;
  const float* wcv  = ws + WS_WCONV;
  const float* wsum = ws + WS_WSUM;
  const float* kb   = ws + WS_KB;
  u16* inbf = (u16*)(ws + WS_INBF) + (size_t)n*KPAD;

  // ---- phase A: in-wave idx/weights; batched gather (8x16B in flight) ----
  int l16 = tid & 15;
  int j16 = nind[n*16 + l16];
  float d16 = ndist[n*16 + l16];
  float inv = 1.f/(d16 + 1e-8f);
  float ssum = inv;
  #pragma unroll
  for (int off=8; off; off>>=1) ssum += __shfl_xor(ssum, off, 16);
  float w16 = inv / ssum;

  int klo = tid >> 6;          // 0..3 : neighbor group
  int c4  = (tid & 63) * 4;    // feature base
  float4 xq[4], mq[4];
  float  wq[4];
  #pragma unroll
  for (int q=0;q<4;++q){
    int k = klo*4 + q;
    int j = __shfl(j16, k, 16);
    wq[q] = __shfl(w16, k, 16);
    size_t base = (size_t)j*256 + c4;
    xq[q] = *(const float4*)(Xtr + base);
    mq[q] = *(const float4*)(mtr + base);
  }
  #pragma unroll
  for (int r=0;r<4;++r){
    float v0 = ((const float*)&xq[0])[r] * ((const float*)&mq[0])[r] * wq[0];
    float v1 = ((const float*)&xq[1])[r] * ((const float*)&mq[1])[r] * wq[1];
    float v2 = ((const float*)&xq[2])[r] * ((const float*)&mq[2])[r] * wq[2];
    float v3 = ((const float*)&xq[3])[r] * ((const float*)&mq[3])[r] * wq[3];
    u32* dst = (u32*)&candT[2 + c4 + r][klo*4];
    dst[0] = (u32)f2bf(v0) | ((u32)f2bf(v1) << 16);
    dst[1] = (u32)f2bf(v2) | ((u32)f2bf(v3) << 16);
  }
  if (tid < 6){
    int r = (tid < 2) ? tid : 256 + tid;  // zero rows 0,1,258..261
    u32* dst = (u32*)&candT[r][0];
    #pragma unroll
    for (int q=0;q<12;q++) dst[q] = 0;
  }
  float xv = X[n*256+tid];
  x_sh[tid] = xv;
  float part = xv * mb[n*256+tid] * vsrc[tid];
  #pragma unroll
  for (int off=32; off; off>>=1) part += __shfl_xor(part, off, 64);
  if ((tid&63)==0) red_sh[tid>>6] = part;
  if (tid < 16){
    float pp = ytr[j16] * w16;
    #pragma unroll
    for (int off=8; off; off>>=1) pp += __shfl_xor(pp, off, 16);
    if (tid==0) pred_sh = pp;
  }
  __syncthreads();   // B1

  // ---- phase C ----
  // h_c from weighted bf16, divided by weight
  {
    int k = tid>>4, d0 = tid&15;
    float s = 0.f;
    #pragma unroll
    for (int i=0;i<16;i++){
      int d = d0 + i*16;
      s += bf2f((u16)candT[2+d][k]) * vdst[d];
    }
    #pragma unroll
    for (int off=8; off; off>>=1) s += __shfl_xor(s, off, 16);
    float wk = __shfl(w16, k, 16);
    if (d0==0) hc_sh[k] = s / wk;
  }
  // correction terms from candT
  if (tid < 160){
    const int tt[10] = {4,3,4,2,3,4,1,2,3,4};
    const int pp[10] = {0,0,1,0,1,2,0,1,2,3};
    int pair = tid >> 4, co = tid & 15;
    int t = tt[pair], p = pp[pair];
    float s = 0.f;
    #pragma unroll
    for (int ci=0; ci<16; ++ci)
      s += wcv[(ci*5+t)*16+co] * bf2f((u16)candT[2+p][ci]);
    corr_sh[pair][co] = s;
  }
  // im1 (wsum conv); tid>=254 corrected in phase D
  float im1;
  {
    float a2[16];
    #pragma unroll
    for (int j=0;j<16;j++) a2[j] = kb[j];
    #pragma unroll
    for (int t=0;t<5;++t){
      int pos = tid + t - 2;
      float v = x_sh[pos & 255];
      v = (pos >= 0 && pos < 256) ? v : 0.f;
      const float* wb_ = wsum + t*16;
      #pragma unroll
      for (int j=0;j<16;j++) a2[j] = fmaf(v, wb_[j], a2[j]);
    }
    im1 = a2[0];
    #pragma unroll
    for (int j=1;j<16;j++) im1 = fmaxf(im1, a2[j]);
  }
  // X1
  float x1v = ws[WS_C1B];
  #pragma unroll
  for (int t=0;t<3;++t){
    int pos = tid + t - 1;
    float v = x_sh[pos & 255];
    v = (pos>=0 && pos<256) ? v : 0.f;
    x1v = fmaf(v, ws[WS_C1W+t], x1v);
  }
  // Neighbors conv via MFMA, swapped operands: C[co][l] -> cheap co-max
  {
    int lane = tid & 63, wave = tid >> 6;
    int g    = lane >> 4;
    int lm   = lane & 15;
    int colh = g & 1;
    int tg   = g >> 1;
    const u16* wb = (const u16*)(ws + WS_WB);
    bf16x8 wfr0 = *(const bf16x8*)(wb + 0*512 + lane*8);
    bf16x8 wfr1 = *(const bf16x8*)(wb + 1*512 + lane*8);
    bf16x8 wfr2 = *(const bf16x8*)(wb + 2*512 + lane*8);
    float4 kb4 = *(const float4*)&kb[g*4];
    #pragma unroll
    for (int i=0;i<4;i++){
      int m0 = (wave*4 + i) * 16;
      f32x4 a = {kb4.x, kb4.y, kb4.z, kb4.w};
      int rbase = m0 + lm + tg;
      bf16x8 cf0 = *(const bf16x8*)&candT[rbase + 0][8*colh];
      a = __builtin_amdgcn_mfma_f32_16x16x32_bf16(wfr0, cf0, a, 0,0,0);
      bf16x8 cf1 = *(const bf16x8*)&candT[rbase + 2][8*colh];
      a = __builtin_amdgcn_mfma_f32_16x16x32_bf16(wfr1, cf1, a, 0,0,0);
      bf16x8 cf2 = *(const bf16x8*)&candT[rbase + 4][8*colh];
      a = __builtin_amdgcn_mfma_f32_16x16x32_bf16(wfr2, cf2, a, 0,0,0);
      float mx = fmaxf(fmaxf(a[0], a[1]), fmaxf(a[2], a[3]));
      mx = fmaxf(mx, __shfl_xor(mx, 16, 64));
      mx = fmaxf(mx, __shfl_xor(mx, 32, 64));
      if (g == 0) nm_sh[m0 + lm] = mx;
    }
  }
  __syncthreads();   // B2

  // ---- phase D ----
  if (tid<16){
    float hx = red_sh[0]+red_sh[1]+red_sh[2]+red_sh[3];
    float e = hx + hc_sh[tid];
    e = (e>=0.f) ? e : 0.2f*e;
    outB[n*16+tid] = e;
    float m = e;
    #pragma unroll
    for (int off=8; off; off>>=1) m = fmaxf(m, __shfl_xor(m, off, 16));
    float ex = __expf(e - m);
    float s2 = ex;
    #pragma unroll
    for (int off=8; off; off>>=1) s2 += __shfl_xor(s2, off, 16);
    outA[n*16+tid] = ex/s2;
  }
  float nm = nm_sh[tid];
  if (tid >= 254){
    float a2[16];
    #pragma unroll
    for (int j=0;j<16;j++) a2[j] = kb[j];
    #pragma unroll
    for (int t=0;t<5;++t){
      int pos = tid + t - 2;
      float v = (pos < 256) ? x_sh[pos] : 0.f;
      const float* wb_ = wsum + t*16;
      #pragma unroll
      for (int j=0;j<16;j++) a2[j] = fmaf(v, wb_[j], a2[j]);
    }
    if (tid == 254){
      #pragma unroll
      for (int j=0;j<16;j++) a2[j] += corr_sh[0][j];
    } else {
      #pragma unroll
      for (int j=0;j<16;j++) a2[j] += corr_sh[1][j] + corr_sh[2][j];
    }
    im1 = a2[0];
    #pragma unroll
    for (int j=1;j<16;j++) im1 = fmaxf(im1, a2[j]);
  }
  float im2 = nm;
  if (tid < 2){
    float a3[16];
    if (tid == 0){
      #pragma unroll
      for (int j=0;j<16;j++)
        a3[j] = kb[j] + wsum[0*16+j]*x_sh[254] + wsum[1*16+j]*x_sh[255]
              + corr_sh[3][j] + corr_sh[4][j] + corr_sh[5][j];
    } else {
      #pragma unroll
      for (int j=0;j<16;j++)
        a3[j] = kb[j] + wsum[0*16+j]*x_sh[255]
              + corr_sh[6][j] + corr_sh[7][j] + corr_sh[8][j] + corr_sh[9][j];
    }
    im2 = a3[0];
    #pragma unroll
    for (int j=1;j<16;j++) im2 = fmaxf(im2, a3[j]);
  }

  inbf[1 + tid]   = f2bf(x1v);
  inbf[257 + tid] = f2bf(im1);
  inbf[513 + tid] = f2bf(im2);
  inbf[769 + tid] = f2bf(nm);
  if (tid == 0){ inbf[0] = f2bf(pred_sh); ws[WS_PRED + n] = pred_sh; }
  if (tid < 63) inbf[1025 + tid] = 0;
}

// ---------------- K2b: bf16 MFMA GEMM, pipelined loads ----------------
__global__ __launch_bounds__(256) void k2b_mlp(
    const float* __restrict__ ws, const float* __restrict__ w3, const float* __restrict__ b3,
    float* __restrict__ out0){
  __shared__ __align__(16) u16 A_sh[32][72];
  __shared__ __align__(16) u16 B_sh[256][72];
  __shared__ float pr[32][2];
  int tid = threadIdx.x;
  int r0 = blockIdx.x * 32;
  const u16* inbf = (const u16*)(ws + WS_INBF);
  const u16* w12t = (const u16*)(ws + WS_W12T);
  int lane = tid & 63, wv = tid >> 6;
  int lm = lane & 15, g = lane >> 4;
  int mt = wv & 1, nh = wv >> 1;
  f32x4 acc[8];
  #pragma unroll
  for (int q=0;q<8;q++){
    float b = ws[WS_B12 + (nh*8+q)*16 + lm];
    acc[q][0]=b; acc[q][1]=b; acc[q][2]=b; acc[q][3]=b;
  }
  int arow = tid >> 3, ak0 = (tid & 7)*8;
  const u16* ap = inbf + (size_t)(r0+arow)*KPAD + ak0;
  const u16* bp = w12t + (size_t)tid*KPAD;
  bf16x8 aR = *(const bf16x8*)ap;
  bf16x8 bR[8];
  #pragma unroll
  for (int j=0;j<8;j++) bR[j] = *(const bf16x8*)(bp + 8*j);
  for (int kt=0; kt<17; ++kt){
    if (kt) __syncthreads();      // WAR vs previous iter's LDS reads
    *(bf16x8*)&A_sh[arow][ak0] = aR;
    #pragma unroll
    for (int j=0;j<8;j++) *(bf16x8*)&B_sh[tid][8*j] = bR[j];
    __syncthreads();
    if (kt < 16){
      aR = *(const bf16x8*)(ap + (kt+1)*64);
      #pragma unroll
      for (int j=0;j<8;j++) bR[j] = *(const bf16x8*)(bp + (kt+1)*64 + 8*j);
    }
    #pragma unroll
    for (int ks=0; ks<2; ++ks){
      bf16x8 af = *(const bf16x8*)&A_sh[mt*16+lm][ks*32 + g*8];
      #pragma unroll
      for (int q=0;q<8;q++){
        bf16x8 bf_ = *(const bf16x8*)&B_sh[(nh*8+q)*16+lm][ks*32 + g*8];
        acc[q] = __builtin_amdgcn_mfma_f32_16x16x32_bf16(af, bf_, acc[q], 0,0,0);
      }
    }
  }
  float w3v[8];
  #pragma unroll
  for (int q=0;q<8;q++) w3v[q] = w3[(nh*8+q)*16 + lm];
  #pragma unroll
  for (int j=0;j<4;j++){
    float p = 0.f;
    #pragma unroll
    for (int q=0;q<8;q++) p += fmaxf(acc[q][j], 0.f) * w3v[q];
    #pragma unroll
    for (int off=1; off<16; off<<=1) p += __shfl_xor(p, off, 64);
    if (lm == 0) pr[mt*16 + g*4 + j][nh] = p;
  }
  __syncthreads();
  if (tid < 32){
    float s = pr[tid][0] + pr[tid][1] + b3[0];
    out0[r0 + tid] = ws[WS_PRED + r0 + tid] + fmaxf(s, 0.f);
  }
}

// ---------------- Fallback: fused path (ws too small) ----------------
__global__ __launch_bounds__(256) void k2_fused(
    const float* __restrict__ X, const float* __restrict__ Xtr, const float* __restrict__ ytr,
    const float* __restrict__ ndist, const float* __restrict__ mtr, const float* __restrict__ mb,
    const int* __restrict__ nind,
    const float* __restrict__ ws,
    const float* __restrict__ w3, const float* __restrict__ b3,
    float* __restrict__ out0, float* __restrict__ outA, float* __restrict__ outB){
  __shared__ float x_sh[256];
  __shared__ float cand_sh[16][256];
  __shared__ __align__(16) float in_sh[ROWS][1028];
  __shared__ float corr_sh[10][16];
  __shared__ float wgt_sh[16];
  __shared__ int   idx_sh[16];
  __shared__ float red_sh[ROWS][4];
  __shared__ float hx_sh;
  __shared__ float pred_s[ROWS];
  __shared__ float hc_sh[16];

  int n0 = blockIdx.x * ROWS;
  int tid = threadIdx.x;
  const float* vsrc = ws + WS_VSRC;
  const float* vdst = ws + WS_VDST;
  const float* wcv  = ws + WS_WCONV;
  const float* wsum = ws + WS_WSUM;
  const float* kb   = ws + WS_KB;

  for (int r = 0; r < ROWS; ++r){
    int n = n0 + r;
    __syncthreads();
    float xv = X[n*256+tid];
    x_sh[tid] = xv;
    float xm = xv * mb[n*256+tid];
    float part = xm * vsrc[tid];
    #pragma unroll
    for (int off=32; off; off>>=1) part += __shfl_xor(part, off, 64);
    if ((tid&63)==0) red_sh[0][tid>>6] = part;
    __syncthreads();
    if (tid==0) hx_sh = red_sh[0][0]+red_sh[0][1]+red_sh[0][2]+red_sh[0][3];
    if (tid<16){
      int j = nind[n*16+tid];
      idx_sh[tid] = j;
      float d = ndist[n*16+tid];
      float inv = 1.f/(d + 1e-8f);
      float s = inv;
      #pragma unroll
      for (int off=8; off; off>>=1) s += __shfl_xor(s, off, 16);
      float w = inv/s;
      wgt_sh[tid] = w;
      float pp = ytr[j] * w;
      #pragma unroll
      for (int off=8; off; off>>=1) pp += __shfl_xor(pp, off, 16);
      if (tid==0){ pred_s[r] = pp; in_sh[r][0] = pp; }
    }
    __syncthreads();
    {
      int kk4 = tid >> 6;
      int c4 = (tid & 63) * 4;
      #pragma unroll
      for (int g=0; g<4; ++g){
        int k = g*4 + kk4;
        size_t basei = (size_t)idx_sh[k]*256 + c4;
        float4 xv4 = *(const float4*)(Xtr + basei);
        float4 mv4 = *(const float4*)(mtr + basei);
        float4 cv;
        cv.x = xv4.x*mv4.x; cv.y = xv4.y*mv4.y; cv.z = xv4.z*mv4.z; cv.w = xv4.w*mv4.w;
        *(float4*)&cand_sh[k][c4] = cv;
      }
    }
    __syncthreads();
    {
      int k = tid>>4, d0 = tid&15;
      float s = 0.f;
      #pragma unroll
      for (int i=0;i<16;i++){ int d = d0 + i*16; s += cand_sh[k][d]*vdst[d]; }
      #pragma unroll
      for (int off=8; off; off>>=1) s += __shfl_xor(s, off, 16);
      if (d0==0) hc_sh[k] = s;
    }
    __syncthreads();
    if (tid<16){
      float e = hx_sh + hc_sh[tid];
      e = (e>=0.f) ? e : 0.2f*e;
      outB[n*16+tid] = e;
      float m = e;
      #pragma unroll
      for (int off=8; off; off>>=1) m = fmaxf(m, __shfl_xor(m, off, 16));
      float ex = __expf(e - m);
      float ssum = ex;
      #pragma unroll
      for (int off=8; off; off>>=1) ssum += __shfl_xor(ssum, off, 16);
      outA[n*16+tid] = ex/ssum;
    }
    #pragma unroll
    for (int k=0;k<16;k++) cand_sh[k][tid] *= wgt_sh[k];
    __syncthreads();
    if (tid < 160){
      const int tt[10] = {4,3,4,2,3,4,1,2,3,4};
      const int pp[10] = {0,0,1,0,1,2,0,1,2,3};
      int pair = tid >> 4, co = tid & 15;
      int t = tt[pair], p = pp[pair];
      float s = 0.f;
      #pragma unroll
      for (int ci=0; ci<16; ++ci) s += wcv[(ci*5+t)*16+co] * cand_sh[ci][p];
      corr_sh[pair][co] = s;
    }
    float acc[16];
    #pragma unroll
    for (int j=0;j<16;j++) acc[j] = kb[j];
    for (int ci=0; ci<16; ++ci){
      const float* wci = wcv + ci*80;
      #pragma unroll
      for (int t=0;t<5;++t){
        int pos = tid + t - 2;
        float v = cand_sh[ci][pos & 255];
        v = (pos >= 0 && pos < 256) ? v : 0.f;
        const float* wb_ = wci + t*16;
        #pragma unroll
        for (int j=0;j<16;j++) acc[j] = fmaf(v, wb_[j], acc[j]);
      }
    }
    float nm = acc[0];
    #pragma unroll
    for (int j=1;j<16;j++) nm = fmaxf(nm, acc[j]);
    float a2[16];
    #pragma unroll
    for (int j=0;j<16;j++) a2[j] = kb[j];
    #pragma unroll
    for (int t=0;t<5;++t){
      int pos = tid + t - 2;
      float v = x_sh[pos & 255];
      v = (pos >= 0 && pos < 256) ? v : 0.f;
      const float* wb_ = wsum + t*16;
      #pragma unroll
      for (int j=0;j<16;j++) a2[j] = fmaf(v, wb_[j], a2[j]);
    }
    __syncthreads();
    if (tid == 254){
      #pragma unroll
      for (int j=0;j<16;j++) a2[j] += corr_sh[0][j];
    }
    if (tid == 255){
      #pragma unroll
      for (int j=0;j<16;j++) a2[j] += corr_sh[1][j] + corr_sh[2][j];
    }
    float im1 = a2[0];
    #pragma unroll
    for (int j=1;j<16;j++) im1 = fmaxf(im1, a2[j]);
    float im2 = nm;
    if (tid < 2){
      float a3[16];
      if (tid == 0){
        #pragma unroll
        for (int j=0;j<16;j++)
          a3[j] = kb[j] + wsum[0*16+j]*x_sh[254] + wsum[1*16+j]*x_sh[255]
                + corr_sh[3][j] + corr_sh[4][j] + corr_sh[5][j];
      } else {
        #pragma unroll
        for (int j=0;j<16;j++)
          a3[j] = kb[j] + wsum[0*16+j]*x_sh[255]
                + corr_sh[6][j] + corr_sh[7][j] + corr_sh[8][j] + corr_sh[9][j];
      }
      im2 = a3[0];
      #pragma unroll
      for (int j=1;j<16;j++) im2 = fmaxf(im2, a3[j]);
    }
    float x1v = ws[WS_C1B];
    #pragma unroll
    for (int t=0;t<3;++t){
      int pos = tid + t - 1;
      float v = x_sh[pos & 255];
      v = (pos>=0 && pos<256) ? v : 0.f;
      x1v = fmaf(v, ws[WS_C1W+t], x1v);
    }
    in_sh[r][1 + tid]   = x1v;
    in_sh[r][257 + tid] = im1;
    in_sh[r][513 + tid] = im2;
    in_sh[r][769 + tid] = nm;
  }
  __syncthreads();
  const float* W12 = ws + WS_W12;
  float b12v = ws[WS_B12 + tid];
  float z[ROWS];
  #pragma unroll
  for (int r=0;r<ROWS;r++) z[r] = b12v;
  for (int c=0; c<1024; c+=4){
    float w0 = W12[(size_t)(c+0)*256 + tid];
    float w1v = W12[(size_t)(c+1)*256 + tid];
    float w2v = W12[(size_t)(c+2)*256 + tid];
    float w3v_ = W12[(size_t)(c+3)*256 + tid];
    #pragma unroll
    for (int r=0;r<ROWS;r++){
      float4 iv = *(const float4*)&in_sh[r][c];
      z[r] = fmaf(iv.x, w0, z[r]);
      z[r] = fmaf(iv.y, w1v, z[r]);
      z[r] = fmaf(iv.z, w2v, z[r]);
      z[r] = fmaf(iv.w, w3v_, z[r]);
    }
  }
  {
    float wl = W12[(size_t)1024*256 + tid];
    #pragma unroll
    for (int r=0;r<ROWS;r++) z[r] = fmaf(in_sh[r][1024], wl, z[r]);
  }
  float w3v = w3[tid];
  #pragma unroll
  for (int r=0;r<ROWS;r++){
    float p = fmaxf(z[r], 0.f) * w3v;
    #pragma unroll
    for (int off=32; off; off>>=1) p += __shfl_xor(p, off, 64);
    if ((tid&63)==0) red_sh[r][tid>>6] = p;
  }
  __syncthreads();
  if (tid < ROWS){
    float s = red_sh[tid][0]+red_sh[tid][1]+red_sh[tid][2]+red_sh[tid][3] + b3[0];
    float x3 = fmaxf(s, 0.f);
    out0[n0 + tid] = pred_s[tid] + x3;
  }
}

extern "C" void kernel_launch(void* const* d_in, const int* in_sizes, int n_in,
                              void* d_out, int out_size, void* d_ws, size_t ws_size,
                              hipStream_t stream){
  const float* X    = (const float*)d_in[0];
  const float* Xtr  = (const float*)d_in[1];
  const float* ytr  = (const float*)d_in[2];
  const float* nd   = (const float*)d_in[3];
  const float* mtr  = (const float*)d_in[4];
  const float* mb   = (const float*)d_in[5];
  const float* Watt = (const float*)d_in[6];
  const float* asrc = (const float*)d_in[7];
  const float* adst = (const float*)d_in[8];
  const float* w1   = (const float*)d_in[9];
  const float* b1   = (const float*)d_in[10];
  const float* w2   = (const float*)d_in[11];
  const float* b2   = (const float*)d_in[12];
  const float* w3   = (const float*)d_in[13];
  const float* b3   = (const float*)d_in[14];
  const float* c1w  = (const float*)d_in[15];
  const float* c1b  = (const float*)d_in[16];
  const float* ckw  = (const float*)d_in[17];
  const float* ckb  = (const float*)d_in[18];
  const int* nind = (const int*)d_in[19];
  float* ws = (float*)d_ws;
  float* out0 = (float*)d_out;
  float* outA = out0 + NO;
  float* outB = out0 + NO + NO*KNN;

  k1_fold<<<dim3(72), dim3(256), 0, stream>>>(w1, w2, Watt, asrc, adst, b1, b2,
                                              c1w, c1b, ckw, ckb, ws);
  if (ws_size >= WS_NEED_BYTES){
    k2a_stage<<<dim3(NO), dim3(256), 0, stream>>>(X, Xtr, ytr, nd, mtr, mb, nind,
                                                  ws, outA, outB);
    k2b_mlp<<<dim3(NO/32), dim3(256), 0, stream>>>((const float*)ws, w3, b3, out0);
  } else {
    k2_fused<<<dim3(NO/ROWS), dim3(256), 0, stream>>>(X, Xtr, ytr, nd, mtr, mb, nind,
                                                      (const float*)ws, w3, b3,
                                                      out0, outA, outB);
  }
}